// Round 1
// baseline (3714.433 us; speedup 1.0000x reference)
//
#include <hip/hip_runtime.h>
#include <hip/hip_bf16.h>
#include <math.h>

// Mamba forward, MI355X. B=1 L=1024 D=1024 DI=2048 S=16 R=64 DC=4 NL=4 VOCAB=32000
// Round 0: correctness-first baseline. bf16 MFMA GEMM (16x16x32), f32 everything else.

typedef __attribute__((ext_vector_type(8))) short bf16x8;
typedef __attribute__((ext_vector_type(4))) float f32x4;

__device__ __forceinline__ short f2bf(float f) {
  union { float f; unsigned u; } v; v.f = f;
  unsigned u = v.u;
  unsigned r = (u + 0x7FFFu + ((u >> 16) & 1u)) >> 16;  // RNE
  return (short)r;
}

__device__ __forceinline__ bf16x8 pack8(float4 a, float4 b) {
  bf16x8 r;
  r[0] = f2bf(a.x); r[1] = f2bf(a.y); r[2] = f2bf(a.z); r[3] = f2bf(a.w);
  r[4] = f2bf(b.x); r[5] = f2bf(b.y); r[6] = f2bf(b.z); r[7] = f2bf(b.w);
  return r;
}

// ---------------- embedding gather ----------------
__global__ __launch_bounds__(256) void embed_k(const int* __restrict__ tok,
                                               const float* __restrict__ emb,
                                               float* __restrict__ x) {
  int l = blockIdx.x;
  int t = tok[l];
  const float4* src = (const float4*)(emb + (size_t)t * 1024);
  ((float4*)(x + (size_t)l * 1024))[threadIdx.x] = src[threadIdx.x];
}

// ---------------- rmsnorm (row of 1024) ----------------
__global__ __launch_bounds__(256) void rmsnorm_k(const float* __restrict__ x,
                                                 const float* __restrict__ w,
                                                 float* __restrict__ y) {
  int l = blockIdx.x;
  const float4* xr = (const float4*)(x + (size_t)l * 1024);
  float4 v = xr[threadIdx.x];
  float ss = v.x * v.x + v.y * v.y + v.z * v.z + v.w * v.w;
  ss += __shfl_down(ss, 32); ss += __shfl_down(ss, 16); ss += __shfl_down(ss, 8);
  ss += __shfl_down(ss, 4);  ss += __shfl_down(ss, 2);  ss += __shfl_down(ss, 1);
  __shared__ float wsum[4];
  if ((threadIdx.x & 63) == 0) wsum[threadIdx.x >> 6] = ss;
  __syncthreads();
  float tot = wsum[0] + wsum[1] + wsum[2] + wsum[3];
  float sc = rsqrtf(tot * (1.0f / 1024.0f) + 1e-5f);
  float4 wv = ((const float4*)w)[threadIdx.x];
  float4 o;
  o.x = v.x * sc * wv.x; o.y = v.y * sc * wv.y;
  o.z = v.z * sc * wv.z; o.w = v.w * sc * wv.w;
  ((float4*)(y + (size_t)l * 1024))[threadIdx.x] = o;
}

// ---------------- depthwise causal conv (DC=4) + bias + silu ----------------
// in: xz rows stride 4096 (first DI cols), out: u rows stride 2048
__global__ __launch_bounds__(256) void conv_silu_k(const float* __restrict__ xz,
                                                   const float* __restrict__ cw,
                                                   const float* __restrict__ cb,
                                                   float* __restrict__ u) {
  int idx = blockIdx.x * 256 + threadIdx.x;   // l*2048 + d
  int d = idx & 2047;
  int l = idx >> 11;
  float acc = cb[d];
#pragma unroll
  for (int j = 0; j < 4; ++j) {
    int ll = l - 3 + j;
    if (ll >= 0) acc = fmaf(xz[(size_t)ll * 4096 + d], cw[d * 4 + j], acc);
  }
  float sig = 1.0f / (1.0f + __expf(-acc));
  u[idx] = acc * sig;
}

// ---------------- generic GEMM: C[M,N] = A[M,K] @ W[N,K]^T (+ addsrc) ----------------
// bf16 MFMA 16x16x32, tile 128x128, BK=32, 256 threads (4 waves, 2x2 of 64x64).
// grid.x = M/128 (fast, so M-blocks sharing a W panel are co-scheduled), grid.y = ceil(N/128)
__global__ __launch_bounds__(256) void gemm_bt_k(const float* __restrict__ A, int lda,
                                                 const float* __restrict__ W, int ldw,
                                                 const float* __restrict__ addsrc,
                                                 float* __restrict__ C, int ldc,
                                                 int N, int K) {
  const int tid  = threadIdx.x;
  const int srow = tid >> 1;          // 0..127 staging row
  const int skg  = (tid & 1) << 1;    // k-group pair 0 or 2
  const int bm = blockIdx.x << 7;
  const int bn = blockIdx.y << 7;
  const int wid = tid >> 6;
  const int lane = tid & 63;
  const int wm = (wid >> 1) << 6;
  const int wn = (wid & 1) << 6;
  const int fr = lane & 15;
  const int kg = lane >> 4;

  // LDS in k-grouped layout: [kgroup][row] of 8 contiguous bf16 -> conflict-free b128 reads
  __shared__ bf16x8 lA[4][128];
  __shared__ bf16x8 lB[4][128];

  f32x4 zero4 = {0.f, 0.f, 0.f, 0.f};
  f32x4 acc[4][4];
#pragma unroll
  for (int i = 0; i < 4; ++i)
#pragma unroll
    for (int j = 0; j < 4; ++j) acc[i][j] = zero4;

  const bool wvalid = (bn + srow) < N;
  const float* gA = A + (size_t)(bm + srow) * lda + (skg << 3);
  const float* gW = W + (size_t)(wvalid ? (bn + srow) : 0) * ldw + (skg << 3);

  for (int k0 = 0; k0 < K; k0 += 32) {
    float4 a0 = *(const float4*)(gA + k0);
    float4 a1 = *(const float4*)(gA + k0 + 4);
    float4 a2 = *(const float4*)(gA + k0 + 8);
    float4 a3 = *(const float4*)(gA + k0 + 12);
    float4 w0 = make_float4(0.f, 0.f, 0.f, 0.f), w1 = w0, w2 = w0, w3 = w0;
    if (wvalid) {
      w0 = *(const float4*)(gW + k0);
      w1 = *(const float4*)(gW + k0 + 4);
      w2 = *(const float4*)(gW + k0 + 8);
      w3 = *(const float4*)(gW + k0 + 12);
    }
    __syncthreads();   // previous iteration's frag reads done
    lA[skg][srow]     = pack8(a0, a1);
    lA[skg + 1][srow] = pack8(a2, a3);
    lB[skg][srow]     = pack8(w0, w1);
    lB[skg + 1][srow] = pack8(w2, w3);
    __syncthreads();

    bf16x8 af[4], bf_[4];
#pragma unroll
    for (int mi = 0; mi < 4; ++mi) af[mi] = lA[kg][wm + (mi << 4) + fr];
#pragma unroll
    for (int ni = 0; ni < 4; ++ni) bf_[ni] = lB[kg][wn + (ni << 4) + fr];
#pragma unroll
    for (int mi = 0; mi < 4; ++mi)
#pragma unroll
      for (int ni = 0; ni < 4; ++ni)
        acc[mi][ni] = __builtin_amdgcn_mfma_f32_16x16x32_bf16(af[mi], bf_[ni], acc[mi][ni], 0, 0, 0);
  }

#pragma unroll
  for (int mi = 0; mi < 4; ++mi)
#pragma unroll
    for (int ni = 0; ni < 4; ++ni) {
      int n = bn + wn + (ni << 4) + fr;
      if (n < N) {
#pragma unroll
        for (int i = 0; i < 4; ++i) {
          int m = bm + wm + (mi << 4) + (kg << 2) + i;
          size_t off = (size_t)m * ldc + n;
          float v = acc[mi][ni][i];
          if (addsrc) v += addsrc[off];
          C[off] = v;
        }
      }
    }
}

// ---------------- fused selective scan ----------------
// thread = (d-group, s): block 256 = 16 d x 16 s; grid 128 -> d = 0..2047
// dt = softplus(dtraw + dtb); h = exp(dt*A)*h + dt*u*B; y = (sum_s h*C + u*D) * silu(z)
__global__ __launch_bounds__(256) void scan_k(const float* __restrict__ dtr,
                                              const float* __restrict__ u,
                                              const float* __restrict__ dbc,
                                              const float* __restrict__ xz,
                                              const float* __restrict__ A_log,
                                              const float* __restrict__ Dp,
                                              const float* __restrict__ dtb,
                                              float* __restrict__ y) {
  int tid = threadIdx.x;
  int s = tid & 15, dg = tid >> 4;
  int d = (blockIdx.x << 4) + dg;
  float A = -__expf(A_log[d * 16 + s]);
  float dpar = Dp[d];
  float bias = dtb[d];
  float h = 0.f;

  // 1-deep software prefetch
  float dt_n = dtr[d];
  float u_n  = u[d];
  float B_n  = dbc[64 + s];
  float C_n  = dbc[80 + s];
  float z_n  = xz[2048 + d];

  for (int l = 0; l < 1024; ++l) {
    float dtv = dt_n + bias;
    float uv = u_n, Bv = B_n, Cv = C_n, zv = z_n;
    if (l < 1023) {
      size_t r2 = (size_t)(l + 1) * 2048 + d;
      dt_n = dtr[r2];
      u_n  = u[r2];
      B_n  = dbc[(l + 1) * 96 + 64 + s];
      C_n  = dbc[(l + 1) * 96 + 80 + s];
      z_n  = xz[(size_t)(l + 1) * 4096 + 2048 + d];
    }
    dtv = (dtv > 20.f) ? dtv : log1pf(__expf(dtv));
    float dA = __expf(dtv * A);
    h = fmaf(dA, h, dtv * uv * Bv);
    float p = h * Cv;
    p += __shfl_xor(p, 1); p += __shfl_xor(p, 2);
    p += __shfl_xor(p, 4); p += __shfl_xor(p, 8);
    if (s == 0) {
      float sig = 1.0f / (1.0f + __expf(-zv));
      y[(size_t)l * 2048 + d] = (p + uv * dpar) * (zv * sig);
    }
  }
}

// ---------------- host launch ----------------
extern "C" void kernel_launch(void* const* d_in, const int* in_sizes, int n_in,
                              void* d_out, int out_size, void* d_ws, size_t ws_size,
                              hipStream_t stream) {
  const int*   tokens = (const int*)d_in[0];
  const float* embed  = (const float*)d_in[1];
  const float* norm_w = (const float*)d_in[2];
  const float* in_w   = (const float*)d_in[3];
  const float* conv_w = (const float*)d_in[4];
  const float* conv_b = (const float*)d_in[5];
  const float* x_w    = (const float*)d_in[6];
  const float* dt_w   = (const float*)d_in[7];
  const float* dt_b   = (const float*)d_in[8];
  const float* A_log  = (const float*)d_in[9];
  const float* D_par  = (const float*)d_in[10];
  const float* out_w  = (const float*)d_in[11];
  const float* normf  = (const float*)d_in[12];
  const float* lm_w   = (const float*)d_in[13];

  float* out = (float*)d_out;
  // scratch carved out of d_out (48.4 MB of 131 MB; fully overwritten by final GEMM)
  float* x   = out;                     // 1024x1024
  float* xn  = x   + 1024 * 1024;      // 1024x1024
  float* xz  = xn  + 1024 * 1024;      // 1024x4096
  float* u   = xz  + 1024 * 4096;      // 1024x2048
  float* dtr = u   + 1024 * 2048;      // 1024x2048
  float* y   = dtr + 1024 * 2048;      // 1024x2048
  float* dbc = y   + 1024 * 2048;      // 1024x96
  float* xnf = (float*)d_ws;           // 1024x1024 (must survive lm_head)

  embed_k<<<1024, 256, 0, stream>>>(tokens, embed, x);

  for (int i = 0; i < 4; ++i) {
    rmsnorm_k<<<1024, 256, 0, stream>>>(x, norm_w + i * 1024, xn);
    gemm_bt_k<<<dim3(8, 32), 256, 0, stream>>>(xn, 1024, in_w + (size_t)i * 4096 * 1024, 1024,
                                               nullptr, xz, 4096, 4096, 1024);
    conv_silu_k<<<8192, 256, 0, stream>>>(xz, conv_w + i * 2048 * 4, conv_b + i * 2048, u);
    gemm_bt_k<<<dim3(8, 1), 256, 0, stream>>>(u, 2048, x_w + i * 96 * 2048, 2048,
                                              nullptr, dbc, 96, 96, 2048);
    gemm_bt_k<<<dim3(8, 16), 256, 0, stream>>>(dbc, 96, dt_w + i * 2048 * 64, 64,
                                               nullptr, dtr, 2048, 2048, 64);
    scan_k<<<128, 256, 0, stream>>>(dtr, u, dbc, xz, A_log + i * 2048 * 16,
                                    D_par + i * 2048, dt_b + i * 2048, y);
    gemm_bt_k<<<dim3(8, 8), 256, 0, stream>>>(y, 2048, out_w + (size_t)i * 1024 * 2048, 2048,
                                              x, x, 1024, 1024, 2048);
  }

  rmsnorm_k<<<1024, 256, 0, stream>>>(x, normf, xnf);
  gemm_bt_k<<<dim3(8, 250), 256, 0, stream>>>(xnf, 1024, lm_w, 1024,
                                              nullptr, out, 32000, 32000, 1024);
}

// Round 2
// 2222.352 us; speedup vs baseline: 1.6714x; 1.6714x over previous
//
#include <hip/hip_runtime.h>
#include <hip/hip_bf16.h>
#include <math.h>

// Mamba forward, MI355X. B=1 L=1024 D=1024 DI=2048 S=16 R=64 DC=4 NL=4 VOCAB=32000
// Round 1: chunk-parallel selective scan (32 chunks x 32 steps, 3 passes).

typedef __attribute__((ext_vector_type(8))) short bf16x8;
typedef __attribute__((ext_vector_type(4))) float f32x4;

__device__ __forceinline__ short f2bf(float f) {
  union { float f; unsigned u; } v; v.f = f;
  unsigned u = v.u;
  unsigned r = (u + 0x7FFFu + ((u >> 16) & 1u)) >> 16;  // RNE
  return (short)r;
}

__device__ __forceinline__ bf16x8 pack8(float4 a, float4 b) {
  bf16x8 r;
  r[0] = f2bf(a.x); r[1] = f2bf(a.y); r[2] = f2bf(a.z); r[3] = f2bf(a.w);
  r[4] = f2bf(b.x); r[5] = f2bf(b.y); r[6] = f2bf(b.z); r[7] = f2bf(b.w);
  return r;
}

__device__ __forceinline__ float softplus_f(float x) {
  return (x > 20.f) ? x : log1pf(__expf(x));
}

// ---------------- embedding gather ----------------
__global__ __launch_bounds__(256) void embed_k(const int* __restrict__ tok,
                                               const float* __restrict__ emb,
                                               float* __restrict__ x) {
  int l = blockIdx.x;
  int t = tok[l];
  const float4* src = (const float4*)(emb + (size_t)t * 1024);
  ((float4*)(x + (size_t)l * 1024))[threadIdx.x] = src[threadIdx.x];
}

// ---------------- rmsnorm (row of 1024) ----------------
__global__ __launch_bounds__(256) void rmsnorm_k(const float* __restrict__ x,
                                                 const float* __restrict__ w,
                                                 float* __restrict__ y) {
  int l = blockIdx.x;
  const float4* xr = (const float4*)(x + (size_t)l * 1024);
  float4 v = xr[threadIdx.x];
  float ss = v.x * v.x + v.y * v.y + v.z * v.z + v.w * v.w;
  ss += __shfl_down(ss, 32); ss += __shfl_down(ss, 16); ss += __shfl_down(ss, 8);
  ss += __shfl_down(ss, 4);  ss += __shfl_down(ss, 2);  ss += __shfl_down(ss, 1);
  __shared__ float wsum[4];
  if ((threadIdx.x & 63) == 0) wsum[threadIdx.x >> 6] = ss;
  __syncthreads();
  float tot = wsum[0] + wsum[1] + wsum[2] + wsum[3];
  float sc = rsqrtf(tot * (1.0f / 1024.0f) + 1e-5f);
  float4 wv = ((const float4*)w)[threadIdx.x];
  float4 o;
  o.x = v.x * sc * wv.x; o.y = v.y * sc * wv.y;
  o.z = v.z * sc * wv.z; o.w = v.w * sc * wv.w;
  ((float4*)(y + (size_t)l * 1024))[threadIdx.x] = o;
}

// ---------------- depthwise causal conv (DC=4) + bias + silu ----------------
__global__ __launch_bounds__(256) void conv_silu_k(const float* __restrict__ xz,
                                                   const float* __restrict__ cw,
                                                   const float* __restrict__ cb,
                                                   float* __restrict__ u) {
  int idx = blockIdx.x * 256 + threadIdx.x;   // l*2048 + d
  int d = idx & 2047;
  int l = idx >> 11;
  float acc = cb[d];
#pragma unroll
  for (int j = 0; j < 4; ++j) {
    int ll = l - 3 + j;
    if (ll >= 0) acc = fmaf(xz[(size_t)ll * 4096 + d], cw[d * 4 + j], acc);
  }
  float sig = 1.0f / (1.0f + __expf(-acc));
  u[idx] = acc * sig;
}

// ---------------- generic GEMM: C[M,N] = A[M,K] @ W[N,K]^T (+ addsrc) ----------------
__global__ __launch_bounds__(256) void gemm_bt_k(const float* __restrict__ A, int lda,
                                                 const float* __restrict__ W, int ldw,
                                                 const float* __restrict__ addsrc,
                                                 float* __restrict__ C, int ldc,
                                                 int N, int K) {
  const int tid  = threadIdx.x;
  const int srow = tid >> 1;          // 0..127 staging row
  const int skg  = (tid & 1) << 1;    // k-group pair 0 or 2
  const int bm = blockIdx.x << 7;
  const int bn = blockIdx.y << 7;
  const int wid = tid >> 6;
  const int lane = tid & 63;
  const int wm = (wid >> 1) << 6;
  const int wn = (wid & 1) << 6;
  const int fr = lane & 15;
  const int kg = lane >> 4;

  __shared__ bf16x8 lA[4][128];
  __shared__ bf16x8 lB[4][128];

  f32x4 zero4 = {0.f, 0.f, 0.f, 0.f};
  f32x4 acc[4][4];
#pragma unroll
  for (int i = 0; i < 4; ++i)
#pragma unroll
    for (int j = 0; j < 4; ++j) acc[i][j] = zero4;

  const bool wvalid = (bn + srow) < N;
  const float* gA = A + (size_t)(bm + srow) * lda + (skg << 3);
  const float* gW = W + (size_t)(wvalid ? (bn + srow) : 0) * ldw + (skg << 3);

  for (int k0 = 0; k0 < K; k0 += 32) {
    float4 a0 = *(const float4*)(gA + k0);
    float4 a1 = *(const float4*)(gA + k0 + 4);
    float4 a2 = *(const float4*)(gA + k0 + 8);
    float4 a3 = *(const float4*)(gA + k0 + 12);
    float4 w0 = make_float4(0.f, 0.f, 0.f, 0.f), w1 = w0, w2 = w0, w3 = w0;
    if (wvalid) {
      w0 = *(const float4*)(gW + k0);
      w1 = *(const float4*)(gW + k0 + 4);
      w2 = *(const float4*)(gW + k0 + 8);
      w3 = *(const float4*)(gW + k0 + 12);
    }
    __syncthreads();
    lA[skg][srow]     = pack8(a0, a1);
    lA[skg + 1][srow] = pack8(a2, a3);
    lB[skg][srow]     = pack8(w0, w1);
    lB[skg + 1][srow] = pack8(w2, w3);
    __syncthreads();

    bf16x8 af[4], bf_[4];
#pragma unroll
    for (int mi = 0; mi < 4; ++mi) af[mi] = lA[kg][wm + (mi << 4) + fr];
#pragma unroll
    for (int ni = 0; ni < 4; ++ni) bf_[ni] = lB[kg][wn + (ni << 4) + fr];
#pragma unroll
    for (int mi = 0; mi < 4; ++mi)
#pragma unroll
      for (int ni = 0; ni < 4; ++ni)
        acc[mi][ni] = __builtin_amdgcn_mfma_f32_16x16x32_bf16(af[mi], bf_[ni], acc[mi][ni], 0, 0, 0);
  }

#pragma unroll
  for (int mi = 0; mi < 4; ++mi)
#pragma unroll
    for (int ni = 0; ni < 4; ++ni) {
      int n = bn + wn + (ni << 4) + fr;
      if (n < N) {
#pragma unroll
        for (int i = 0; i < 4; ++i) {
          int m = bm + wm + (mi << 4) + (kg << 2) + i;
          size_t off = (size_t)m * ldc + n;
          float v = acc[mi][ni][i];
          if (addsrc) v += addsrc[off];
          C[off] = v;
        }
      }
    }
}

// ---------------- chunk-parallel selective scan ----------------
// 1024 steps = 32 chunks x 32. h is linear in h0: h_end = P*h0 + q per (d,s).
#define NCH 32
#define CHL 32

// pass1: per-chunk (P,q). grid (128 d-blocks, 32 chunks), block 256 = 16dg x 16s.
__global__ __launch_bounds__(256) void scan_p1_k(const float* __restrict__ dtr,
                                                 const float* __restrict__ u,
                                                 const float* __restrict__ dbc,
                                                 const float* __restrict__ A_log,
                                                 const float* __restrict__ dtb,
                                                 float* __restrict__ Pg,
                                                 float* __restrict__ qg) {
  int tid = threadIdx.x;
  int s = tid & 15, dg = tid >> 4;
  int d = (blockIdx.x << 4) + dg;
  int c = blockIdx.y;
  int l0 = c << 5;
  float A = -__expf(A_log[d * 16 + s]);
  float bias = dtb[d];
  float P = 1.f, q = 0.f;
#pragma unroll 4
  for (int i = 0; i < CHL; ++i) {
    int l = l0 + i;
    float dtv = softplus_f(dtr[(size_t)l * 2048 + d] + bias);
    float dA = __expf(dtv * A);
    float dBu = dtv * u[(size_t)l * 2048 + d] * dbc[l * 96 + 64 + s];
    P *= dA;
    q = fmaf(dA, q, dBu);
  }
  size_t o = (size_t)c * 32768 + d * 16 + s;
  Pg[o] = P;
  qg[o] = q;
}

// pass2: h_start per chunk. 32768 states, 128 blocks x 256.
__global__ __launch_bounds__(256) void scan_p2_k(const float* __restrict__ Pg,
                                                 const float* __restrict__ qg,
                                                 float* __restrict__ hst) {
  int idx = blockIdx.x * 256 + threadIdx.x;   // d*16+s
  float h = 0.f;
#pragma unroll
  for (int c = 0; c < NCH; ++c) {
    size_t o = (size_t)c * 32768 + idx;
    hst[o] = h;
    h = fmaf(Pg[o], h, qg[o]);
  }
}

// pass3: re-run chunk from h_start, emit y = (sum_s h*C + u*D) * silu(z).
__global__ __launch_bounds__(256) void scan_p3_k(const float* __restrict__ dtr,
                                                 const float* __restrict__ u,
                                                 const float* __restrict__ dbc,
                                                 const float* __restrict__ xz,
                                                 const float* __restrict__ A_log,
                                                 const float* __restrict__ Dp,
                                                 const float* __restrict__ dtb,
                                                 const float* __restrict__ hst,
                                                 float* __restrict__ y) {
  int tid = threadIdx.x;
  int s = tid & 15, dg = tid >> 4;
  int d = (blockIdx.x << 4) + dg;
  int c = blockIdx.y;
  int l0 = c << 5;
  float A = -__expf(A_log[d * 16 + s]);
  float dpar = Dp[d];
  float bias = dtb[d];
  float h = hst[(size_t)c * 32768 + d * 16 + s];
#pragma unroll 4
  for (int i = 0; i < CHL; ++i) {
    int l = l0 + i;
    size_t rd = (size_t)l * 2048 + d;
    float dtv = softplus_f(dtr[rd] + bias);
    float uv = u[rd];
    float dA = __expf(dtv * A);
    h = fmaf(dA, h, dtv * uv * dbc[l * 96 + 64 + s]);
    float p = h * dbc[l * 96 + 80 + s];
    p += __shfl_xor(p, 1); p += __shfl_xor(p, 2);
    p += __shfl_xor(p, 4); p += __shfl_xor(p, 8);
    if (s == 0) {
      float zv = xz[(size_t)l * 4096 + 2048 + d];
      float sig = 1.0f / (1.0f + __expf(-zv));
      y[rd] = (p + uv * dpar) * (zv * sig);
    }
  }
}

// ---------------- host launch ----------------
extern "C" void kernel_launch(void* const* d_in, const int* in_sizes, int n_in,
                              void* d_out, int out_size, void* d_ws, size_t ws_size,
                              hipStream_t stream) {
  const int*   tokens = (const int*)d_in[0];
  const float* embed  = (const float*)d_in[1];
  const float* norm_w = (const float*)d_in[2];
  const float* in_w   = (const float*)d_in[3];
  const float* conv_w = (const float*)d_in[4];
  const float* conv_b = (const float*)d_in[5];
  const float* x_w    = (const float*)d_in[6];
  const float* dt_w   = (const float*)d_in[7];
  const float* dt_b   = (const float*)d_in[8];
  const float* A_log  = (const float*)d_in[9];
  const float* D_par  = (const float*)d_in[10];
  const float* out_w  = (const float*)d_in[11];
  const float* normf  = (const float*)d_in[12];
  const float* lm_w   = (const float*)d_in[13];

  float* out = (float*)d_out;
  // scratch carved out of d_out (~64 MB of 131 MB; fully overwritten by final GEMM)
  float* x   = out;                    // 1024x1024
  float* xn  = x   + 1024 * 1024;     // 1024x1024
  float* xz  = xn  + 1024 * 1024;     // 1024x4096
  float* u   = xz  + 1024 * 4096;     // 1024x2048
  float* dtr = u   + 1024 * 2048;     // 1024x2048
  float* y   = dtr + 1024 * 2048;     // 1024x2048
  float* dbc = y   + 1024 * 2048;     // 1024x96
  float* Pg  = dbc + 1024 * 96;       // 32x32768
  float* qg  = Pg  + 32 * 32768;      // 32x32768
  float* hst = qg  + 32 * 32768;      // 32x32768
  float* xnf = (float*)d_ws;          // 1024x1024 (must survive lm_head)

  embed_k<<<1024, 256, 0, stream>>>(tokens, embed, x);

  for (int i = 0; i < 4; ++i) {
    rmsnorm_k<<<1024, 256, 0, stream>>>(x, norm_w + i * 1024, xn);
    gemm_bt_k<<<dim3(8, 32), 256, 0, stream>>>(xn, 1024, in_w + (size_t)i * 4096 * 1024, 1024,
                                               nullptr, xz, 4096, 4096, 1024);
    conv_silu_k<<<8192, 256, 0, stream>>>(xz, conv_w + i * 2048 * 4, conv_b + i * 2048, u);
    gemm_bt_k<<<dim3(8, 1), 256, 0, stream>>>(u, 2048, x_w + i * 96 * 2048, 2048,
                                              nullptr, dbc, 96, 96, 2048);
    gemm_bt_k<<<dim3(8, 16), 256, 0, stream>>>(dbc, 96, dt_w + i * 2048 * 64, 64,
                                               nullptr, dtr, 2048, 2048, 64);
    scan_p1_k<<<dim3(128, NCH), 256, 0, stream>>>(dtr, u, dbc, A_log + i * 2048 * 16,
                                                  dt_b + i * 2048, Pg, qg);
    scan_p2_k<<<128, 256, 0, stream>>>(Pg, qg, hst);
    scan_p3_k<<<dim3(128, NCH), 256, 0, stream>>>(dtr, u, dbc, xz, A_log + i * 2048 * 16,
                                                  D_par + i * 2048, dt_b + i * 2048, hst, y);
    gemm_bt_k<<<dim3(8, 8), 256, 0, stream>>>(y, 2048, out_w + (size_t)i * 1024 * 2048, 2048,
                                              x, x, 1024, 1024, 2048);
  }

  rmsnorm_k<<<1024, 256, 0, stream>>>(x, normf, xnf);
  gemm_bt_k<<<dim3(8, 250), 256, 0, stream>>>(xnf, 1024, lm_w, 1024,
                                              nullptr, out, 32000, 32000, 1024);
}

// Round 3
// 1277.774 us; speedup vs baseline: 2.9070x; 1.7392x over previous
//
#include <hip/hip_runtime.h>
#include <hip/hip_bf16.h>
#include <math.h>

// Mamba forward, MI355X. B=1 L=1024 D=1024 DI=2048 S=16 R=64 DC=4 NL=4 VOCAB=32000
// Round 2: bf16 weights + global_load_lds GEMM (m97 structure, swizzled LDS),
//          softplus fused into dt_proj epilogue, XCD-aware block swizzle.

typedef __attribute__((ext_vector_type(8))) short bf16x8;
typedef __attribute__((ext_vector_type(4))) float f32x4;

__device__ __forceinline__ short f2bf(float f) {
  union { float f; unsigned u; } v; v.f = f;
  unsigned u = v.u;
  unsigned r = (u + 0x7FFFu + ((u >> 16) & 1u)) >> 16;  // RNE
  return (short)r;
}

__device__ __forceinline__ bf16x8 pack8(float4 a, float4 b) {
  bf16x8 r;
  r[0] = f2bf(a.x); r[1] = f2bf(a.y); r[2] = f2bf(a.z); r[3] = f2bf(a.w);
  r[4] = f2bf(b.x); r[5] = f2bf(b.y); r[6] = f2bf(b.z); r[7] = f2bf(b.w);
  return r;
}

__device__ __forceinline__ float softplus_f(float x) {
  return (x > 20.f) ? x : log1pf(__expf(x));
}

__device__ __forceinline__ void gl_lds16(const void* g, void* l) {
  void* gnc = (void*)g;
  __builtin_amdgcn_global_load_lds((__attribute__((address_space(1))) void*)gnc,
                                   (__attribute__((address_space(3))) void*)l, 16, 0, 0);
}

// ---------------- f32 -> bf16 bulk convert ----------------
__global__ __launch_bounds__(256) void cvt_bf16_k(const float* __restrict__ in,
                                                  unsigned short* __restrict__ out, int n8) {
  int stride = gridDim.x * 256;
  for (int i = blockIdx.x * 256 + threadIdx.x; i < n8; i += stride) {
    const float4* p = (const float4*)(in + (size_t)i * 8);
    float4 a = p[0], b = p[1];
    *(bf16x8*)(out + (size_t)i * 8) = pack8(a, b);
  }
}

// ---------------- embedding gather ----------------
__global__ __launch_bounds__(256) void embed_k(const int* __restrict__ tok,
                                               const float* __restrict__ emb,
                                               float* __restrict__ x) {
  int l = blockIdx.x;
  int t = tok[l];
  const float4* src = (const float4*)(emb + (size_t)t * 1024);
  ((float4*)(x + (size_t)l * 1024))[threadIdx.x] = src[threadIdx.x];
}

// ---------------- rmsnorm -> bf16 out ----------------
__global__ __launch_bounds__(256) void rmsnorm16_k(const float* __restrict__ x,
                                                   const float* __restrict__ w,
                                                   unsigned short* __restrict__ y) {
  int l = blockIdx.x;
  const float4* xr = (const float4*)(x + (size_t)l * 1024);
  float4 v = xr[threadIdx.x];
  float ss = v.x * v.x + v.y * v.y + v.z * v.z + v.w * v.w;
  ss += __shfl_down(ss, 32); ss += __shfl_down(ss, 16); ss += __shfl_down(ss, 8);
  ss += __shfl_down(ss, 4);  ss += __shfl_down(ss, 2);  ss += __shfl_down(ss, 1);
  __shared__ float wsum[4];
  if ((threadIdx.x & 63) == 0) wsum[threadIdx.x >> 6] = ss;
  __syncthreads();
  float tot = wsum[0] + wsum[1] + wsum[2] + wsum[3];
  float sc = rsqrtf(tot * (1.0f / 1024.0f) + 1e-5f);
  float4 wv = ((const float4*)w)[threadIdx.x];
  ushort4 o;
  o.x = (unsigned short)f2bf(v.x * sc * wv.x);
  o.y = (unsigned short)f2bf(v.y * sc * wv.y);
  o.z = (unsigned short)f2bf(v.z * sc * wv.z);
  o.w = (unsigned short)f2bf(v.w * sc * wv.w);
  *(ushort4*)(y + (size_t)l * 1024 + threadIdx.x * 4) = o;
}

// ---------------- rmsnorm f32 out (fallback) ----------------
__global__ __launch_bounds__(256) void rmsnorm_k(const float* __restrict__ x,
                                                 const float* __restrict__ w,
                                                 float* __restrict__ y) {
  int l = blockIdx.x;
  const float4* xr = (const float4*)(x + (size_t)l * 1024);
  float4 v = xr[threadIdx.x];
  float ss = v.x * v.x + v.y * v.y + v.z * v.z + v.w * v.w;
  ss += __shfl_down(ss, 32); ss += __shfl_down(ss, 16); ss += __shfl_down(ss, 8);
  ss += __shfl_down(ss, 4);  ss += __shfl_down(ss, 2);  ss += __shfl_down(ss, 1);
  __shared__ float wsum[4];
  if ((threadIdx.x & 63) == 0) wsum[threadIdx.x >> 6] = ss;
  __syncthreads();
  float tot = wsum[0] + wsum[1] + wsum[2] + wsum[3];
  float sc = rsqrtf(tot * (1.0f / 1024.0f) + 1e-5f);
  float4 wv = ((const float4*)w)[threadIdx.x];
  float4 o;
  o.x = v.x * sc * wv.x; o.y = v.y * sc * wv.y;
  o.z = v.z * sc * wv.z; o.w = v.w * sc * wv.w;
  ((float4*)(y + (size_t)l * 1024))[threadIdx.x] = o;
}

// ---------------- depthwise causal conv + bias + silu (f32 + bf16 out) ----------------
__global__ __launch_bounds__(256) void conv_silu_k(const float* __restrict__ xz,
                                                   const float* __restrict__ cw,
                                                   const float* __restrict__ cb,
                                                   float* __restrict__ u,
                                                   unsigned short* __restrict__ u16) {
  int idx = blockIdx.x * 256 + threadIdx.x;   // l*2048 + d
  int d = idx & 2047;
  int l = idx >> 11;
  float acc = cb[d];
#pragma unroll
  for (int j = 0; j < 4; ++j) {
    int ll = l - 3 + j;
    if (ll >= 0) acc = fmaf(xz[(size_t)ll * 4096 + d], cw[d * 4 + j], acc);
  }
  float sig = 1.0f / (1.0f + __expf(-acc));
  float v = acc * sig;
  u[idx] = v;
  if (u16) u16[idx] = (unsigned short)f2bf(v);
}

// ============ bf16 GEMM, m97 structure ============
// C[M,N] = A[M,K](bf16) @ W[N,K]^T(bf16). Tile 128x128, BK=64, 256 thr (2x2 waves).
// global_load_lds w/ pre-swizzled per-lane source; ds_read_b128 with XOR swizzle.
// 1D grid = gx*gy blocks, bijective XCD swizzle; bm tile = id%gx (gx = M/128).
// Optional: addsrc (f32 residual), spbias (C = softplus(acc+spbias[n])), C16 (bf16 copy).
__global__ __launch_bounds__(256) void gemm16_k(const unsigned short* __restrict__ A, int lda,
                                                const unsigned short* __restrict__ W, int ldw,
                                                const float* __restrict__ addsrc,
                                                const float* __restrict__ spbias,
                                                float* __restrict__ C, int ldc,
                                                unsigned short* __restrict__ C16,
                                                int gx, int N, int K) {
  // bijective XCD-aware remap (m204)
  int total = gridDim.x;
  int lin = blockIdx.x;
  int q = total >> 3, r = total & 7;
  int xcd = lin & 7, idx = lin >> 3;
  int nl = (xcd < r ? xcd * (q + 1) : r * (q + 1) + (xcd - r) * q) + idx;
  const int bm = (nl % gx) << 7;
  const int bn = (nl / gx) << 7;

  const int tid = threadIdx.x;
  const int wid = tid >> 6;
  const int lane = tid & 63;
  const int wm = (wid >> 1) << 6;
  const int wn = (wid & 1) << 6;
  const int fr = lane & 15;
  const int kg = lane >> 4;

  __shared__ unsigned short sA[128 * 64];
  __shared__ unsigned short sB[128 * 64];

  const int srow = lane >> 3;  // 0..7
  const int sch  = lane & 7;   // chunk 0..7 (16B each)

  f32x4 acc[4][4];
#pragma unroll
  for (int i = 0; i < 4; ++i)
#pragma unroll
    for (int j = 0; j < 4; ++j) acc[i][j] = (f32x4){0.f, 0.f, 0.f, 0.f};

  for (int k0 = 0; k0 < K; k0 += 64) {
    __syncthreads();   // prior iteration's frag reads complete
#pragma unroll
    for (int t = 0; t < 4; ++t) {
      int g = (wid << 2) + t;          // 8-row group 0..15
      int row = (g << 3) + srow;       // 0..127
      int xch = sch ^ srow;            // swizzled source chunk
      const unsigned short* ga = A + (size_t)(bm + row) * lda + k0 + (xch << 3);
      int wrow = bn + row; if (wrow >= N) wrow = N - 1;
      const unsigned short* gw = W + (size_t)wrow * ldw + k0 + (xch << 3);
      gl_lds16(ga, &sA[g << 9]);
      gl_lds16(gw, &sB[g << 9]);
    }
    __syncthreads();   // staging (vmcnt-drained) visible

#pragma unroll
    for (int ks = 0; ks < 2; ++ks) {
      bf16x8 af[4], bw[4];
#pragma unroll
      for (int mi = 0; mi < 4; ++mi) {
        int row = wm + (mi << 4) + fr;
        int xch = ((ks << 2) + kg) ^ (fr & 7);
        af[mi] = *(const bf16x8*)&sA[(row << 6) + (xch << 3)];
      }
#pragma unroll
      for (int ni = 0; ni < 4; ++ni) {
        int row = wn + (ni << 4) + fr;
        int xch = ((ks << 2) + kg) ^ (fr & 7);
        bw[ni] = *(const bf16x8*)&sB[(row << 6) + (xch << 3)];
      }
#pragma unroll
      for (int mi = 0; mi < 4; ++mi)
#pragma unroll
        for (int ni = 0; ni < 4; ++ni)
          acc[mi][ni] = __builtin_amdgcn_mfma_f32_16x16x32_bf16(af[mi], bw[ni], acc[mi][ni], 0, 0, 0);
    }
  }

#pragma unroll
  for (int mi = 0; mi < 4; ++mi)
#pragma unroll
    for (int ni = 0; ni < 4; ++ni) {
      int n = bn + wn + (ni << 4) + fr;
      if (n < N) {
#pragma unroll
        for (int i = 0; i < 4; ++i) {
          int m = bm + wm + (mi << 4) + (kg << 2) + i;
          size_t off = (size_t)m * ldc + n;
          float v = acc[mi][ni][i];
          if (addsrc) v += addsrc[off];
          if (spbias) v = softplus_f(v + spbias[n]);
          C[off] = v;
          if (C16) C16[off] = (unsigned short)f2bf(v);
        }
      }
    }
}

// ---------------- f32 GEMM (fallback only) ----------------
__global__ __launch_bounds__(256) void gemm_bt_k(const float* __restrict__ A, int lda,
                                                 const float* __restrict__ W, int ldw,
                                                 const float* __restrict__ addsrc,
                                                 float* __restrict__ C, int ldc,
                                                 int N, int K) {
  const int tid  = threadIdx.x;
  const int srow = tid >> 1;
  const int skg  = (tid & 1) << 1;
  const int bm = blockIdx.x << 7;
  const int bn = blockIdx.y << 7;
  const int wid = tid >> 6;
  const int lane = tid & 63;
  const int wm = (wid >> 1) << 6;
  const int wn = (wid & 1) << 6;
  const int fr = lane & 15;
  const int kg = lane >> 4;

  __shared__ bf16x8 lA[4][128];
  __shared__ bf16x8 lB[4][128];

  f32x4 zero4 = {0.f, 0.f, 0.f, 0.f};
  f32x4 acc[4][4];
#pragma unroll
  for (int i = 0; i < 4; ++i)
#pragma unroll
    for (int j = 0; j < 4; ++j) acc[i][j] = zero4;

  const bool wvalid = (bn + srow) < N;
  const float* gA = A + (size_t)(bm + srow) * lda + (skg << 3);
  const float* gW = W + (size_t)(wvalid ? (bn + srow) : 0) * ldw + (skg << 3);

  for (int k0 = 0; k0 < K; k0 += 32) {
    float4 a0 = *(const float4*)(gA + k0);
    float4 a1 = *(const float4*)(gA + k0 + 4);
    float4 a2 = *(const float4*)(gA + k0 + 8);
    float4 a3 = *(const float4*)(gA + k0 + 12);
    float4 w0 = make_float4(0.f, 0.f, 0.f, 0.f), w1 = w0, w2 = w0, w3 = w0;
    if (wvalid) {
      w0 = *(const float4*)(gW + k0);
      w1 = *(const float4*)(gW + k0 + 4);
      w2 = *(const float4*)(gW + k0 + 8);
      w3 = *(const float4*)(gW + k0 + 12);
    }
    __syncthreads();
    lA[skg][srow]     = pack8(a0, a1);
    lA[skg + 1][srow] = pack8(a2, a3);
    lB[skg][srow]     = pack8(w0, w1);
    lB[skg + 1][srow] = pack8(w2, w3);
    __syncthreads();

    bf16x8 af[4], bf_[4];
#pragma unroll
    for (int mi = 0; mi < 4; ++mi) af[mi] = lA[kg][wm + (mi << 4) + fr];
#pragma unroll
    for (int ni = 0; ni < 4; ++ni) bf_[ni] = lB[kg][wn + (ni << 4) + fr];
#pragma unroll
    for (int mi = 0; mi < 4; ++mi)
#pragma unroll
      for (int ni = 0; ni < 4; ++ni)
        acc[mi][ni] = __builtin_amdgcn_mfma_f32_16x16x32_bf16(af[mi], bf_[ni], acc[mi][ni], 0, 0, 0);
  }

#pragma unroll
  for (int mi = 0; mi < 4; ++mi)
#pragma unroll
    for (int ni = 0; ni < 4; ++ni) {
      int n = bn + wn + (ni << 4) + fr;
      if (n < N) {
#pragma unroll
        for (int i = 0; i < 4; ++i) {
          int m = bm + wm + (mi << 4) + (kg << 2) + i;
          size_t off = (size_t)m * ldc + n;
          float v = acc[mi][ni][i];
          if (addsrc) v += addsrc[off];
          C[off] = v;
        }
      }
    }
}

// ---------------- chunk-parallel scan ----------------
#define NCH 32
#define CHL 32

// fast path: dtv already softplus'ed
__global__ __launch_bounds__(256) void scan_p1f_k(const float* __restrict__ dtv,
                                                  const float* __restrict__ u,
                                                  const float* __restrict__ dbc,
                                                  const float* __restrict__ A_log,
                                                  float* __restrict__ Pg,
                                                  float* __restrict__ qg) {
  int tid = threadIdx.x;
  int s = tid & 15, dg = tid >> 4;
  int d = (blockIdx.x << 4) + dg;
  int c = blockIdx.y;
  int l0 = c << 5;
  float A = -__expf(A_log[d * 16 + s]);
  float P = 1.f, q = 0.f;
#pragma unroll 4
  for (int i = 0; i < CHL; ++i) {
    int l = l0 + i;
    size_t rd = (size_t)l * 2048 + d;
    float dt = dtv[rd];
    float dA = __expf(dt * A);
    P *= dA;
    q = fmaf(dA, q, dt * u[rd] * dbc[l * 96 + 64 + s]);
  }
  size_t o = (size_t)c * 32768 + d * 16 + s;
  Pg[o] = P;
  qg[o] = q;
}

__global__ __launch_bounds__(256) void scan_p2_k(const float* __restrict__ Pg,
                                                 const float* __restrict__ qg,
                                                 float* __restrict__ hst) {
  int idx = blockIdx.x * 256 + threadIdx.x;
  float h = 0.f;
#pragma unroll
  for (int c = 0; c < NCH; ++c) {
    size_t o = (size_t)c * 32768 + idx;
    hst[o] = h;
    h = fmaf(Pg[o], h, qg[o]);
  }
}

__global__ __launch_bounds__(256) void scan_p3f_k(const float* __restrict__ dtv,
                                                  const float* __restrict__ u,
                                                  const float* __restrict__ dbc,
                                                  const float* __restrict__ xz,
                                                  const float* __restrict__ A_log,
                                                  const float* __restrict__ Dp,
                                                  const float* __restrict__ hst,
                                                  unsigned short* __restrict__ y16) {
  int tid = threadIdx.x;
  int s = tid & 15, dg = tid >> 4;
  int d = (blockIdx.x << 4) + dg;
  int c = blockIdx.y;
  int l0 = c << 5;
  float A = -__expf(A_log[d * 16 + s]);
  float dpar = Dp[d];
  float h = hst[(size_t)c * 32768 + d * 16 + s];
#pragma unroll 4
  for (int i = 0; i < CHL; ++i) {
    int l = l0 + i;
    size_t rd = (size_t)l * 2048 + d;
    float dt = dtv[rd];
    float uv = u[rd];
    float dA = __expf(dt * A);
    h = fmaf(dA, h, dt * uv * dbc[l * 96 + 64 + s]);
    float p = h * dbc[l * 96 + 80 + s];
    p += __shfl_xor(p, 1); p += __shfl_xor(p, 2);
    p += __shfl_xor(p, 4); p += __shfl_xor(p, 8);
    if (s == 0) {
      float zv = xz[(size_t)l * 4096 + 2048 + d];
      float sig = 1.0f / (1.0f + __expf(-zv));
      y16[rd] = (unsigned short)f2bf((p + uv * dpar) * (zv * sig));
    }
  }
}

// fallback scan (softplus in-kernel, f32 y)
__global__ __launch_bounds__(256) void scan_p1_k(const float* __restrict__ dtr,
                                                 const float* __restrict__ u,
                                                 const float* __restrict__ dbc,
                                                 const float* __restrict__ A_log,
                                                 const float* __restrict__ dtb,
                                                 float* __restrict__ Pg,
                                                 float* __restrict__ qg) {
  int tid = threadIdx.x;
  int s = tid & 15, dg = tid >> 4;
  int d = (blockIdx.x << 4) + dg;
  int c = blockIdx.y;
  int l0 = c << 5;
  float A = -__expf(A_log[d * 16 + s]);
  float bias = dtb[d];
  float P = 1.f, q = 0.f;
#pragma unroll 4
  for (int i = 0; i < CHL; ++i) {
    int l = l0 + i;
    float dt = softplus_f(dtr[(size_t)l * 2048 + d] + bias);
    float dA = __expf(dt * A);
    P *= dA;
    q = fmaf(dA, q, dt * u[(size_t)l * 2048 + d] * dbc[l * 96 + 64 + s]);
  }
  size_t o = (size_t)c * 32768 + d * 16 + s;
  Pg[o] = P;
  qg[o] = q;
}

__global__ __launch_bounds__(256) void scan_p3_k(const float* __restrict__ dtr,
                                                 const float* __restrict__ u,
                                                 const float* __restrict__ dbc,
                                                 const float* __restrict__ xz,
                                                 const float* __restrict__ A_log,
                                                 const float* __restrict__ Dp,
                                                 const float* __restrict__ dtb,
                                                 const float* __restrict__ hst,
                                                 float* __restrict__ y) {
  int tid = threadIdx.x;
  int s = tid & 15, dg = tid >> 4;
  int d = (blockIdx.x << 4) + dg;
  int c = blockIdx.y;
  int l0 = c << 5;
  float A = -__expf(A_log[d * 16 + s]);
  float dpar = Dp[d];
  float bias = dtb[d];
  float h = hst[(size_t)c * 32768 + d * 16 + s];
#pragma unroll 4
  for (int i = 0; i < CHL; ++i) {
    int l = l0 + i;
    size_t rd = (size_t)l * 2048 + d;
    float dt = softplus_f(dtr[rd] + bias);
    float uv = u[rd];
    float dA = __expf(dt * A);
    h = fmaf(dA, h, dt * uv * dbc[l * 96 + 64 + s]);
    float p = h * dbc[l * 96 + 80 + s];
    p += __shfl_xor(p, 1); p += __shfl_xor(p, 2);
    p += __shfl_xor(p, 4); p += __shfl_xor(p, 8);
    if (s == 0) {
      float zv = xz[(size_t)l * 4096 + 2048 + d];
      float sig = 1.0f / (1.0f + __expf(-zv));
      y[rd] = (p + uv * dpar) * (zv * sig);
    }
  }
}

// ---------------- host launch ----------------
extern "C" void kernel_launch(void* const* d_in, const int* in_sizes, int n_in,
                              void* d_out, int out_size, void* d_ws, size_t ws_size,
                              hipStream_t stream) {
  const int*   tokens = (const int*)d_in[0];
  const float* embed  = (const float*)d_in[1];
  const float* norm_w = (const float*)d_in[2];
  const float* in_w   = (const float*)d_in[3];
  const float* conv_w = (const float*)d_in[4];
  const float* conv_b = (const float*)d_in[5];
  const float* x_w    = (const float*)d_in[6];
  const float* dt_w   = (const float*)d_in[7];
  const float* dt_b   = (const float*)d_in[8];
  const float* A_log  = (const float*)d_in[9];
  const float* D_par  = (const float*)d_in[10];
  const float* out_w  = (const float*)d_in[11];
  const float* normf  = (const float*)d_in[12];
  const float* lm_w   = (const float*)d_in[13];

  float* out = (float*)d_out;
  // f32 scratch in d_out (dead before lm_head writes it)
  float* x    = out;                    // 1M
  float* xz   = x    + 1024 * 1024;    // 4M
  float* u    = xz   + 1024 * 4096;    // 2M
  float* dtv  = u    + 1024 * 2048;    // 2M (fast: softplus'ed; fallback: raw dt)
  float* dbc  = dtv  + 1024 * 2048;    // 96K
  float* Pg   = dbc  + 1024 * 96;      // 1M
  float* qg   = Pg   + 32 * 32768;     // 1M
  float* hst  = qg   + 32 * 32768;     // 1M
  float* xn_f = hst  + 32 * 32768;     // 1M (fallback)
  float* y_f  = xn_f + 1024 * 1024;    // 2M (fallback)
  unsigned short* xn16  = (unsigned short*)(y_f + 1024 * 2048);
  unsigned short* u16   = xn16 + 1024 * 1024;
  unsigned short* y16   = u16  + 1024 * 2048;
  unsigned short* dbc16 = y16  + 1024 * 2048;   // ends ~70.8 MB < 131 MB

  // d_ws: bf16 weights + xnf
  unsigned short* inw16 = (unsigned short*)d_ws;      // 16,777,216
  unsigned short* oww16 = inw16 + 16777216;           //  8,388,608
  unsigned short* xw16  = oww16 + 8388608;            //    786,432
  unsigned short* dtw16 = xw16  + 786432;             //    524,288
  unsigned short* lmw16 = dtw16 + 524288;             // 32,768,000
  unsigned short* xnf16 = lmw16 + 32768000;           //  1,048,576
  const size_t need = (size_t)(16777216 + 8388608 + 786432 + 524288 + 32768000 + 1048576) * 2;
  const bool fast = ws_size >= need;

  embed_k<<<1024, 256, 0, stream>>>(tokens, embed, x);

  if (fast) {
    cvt_bf16_k<<<2048, 256, 0, stream>>>(in_w,  inw16, 2097152);
    cvt_bf16_k<<<1024, 256, 0, stream>>>(out_w, oww16, 1048576);
    cvt_bf16_k<<<384,  256, 0, stream>>>(x_w,   xw16,  98304);
    cvt_bf16_k<<<256,  256, 0, stream>>>(dt_w,  dtw16, 65536);
    cvt_bf16_k<<<2048, 256, 0, stream>>>(lm_w,  lmw16, 4096000);

    for (int i = 0; i < 4; ++i) {
      rmsnorm16_k<<<1024, 256, 0, stream>>>(x, norm_w + i * 1024, xn16);
      gemm16_k<<<256, 256, 0, stream>>>(xn16, 1024, inw16 + (size_t)i * 4194304, 1024,
                                        nullptr, nullptr, xz, 4096, nullptr, 8, 4096, 1024);
      conv_silu_k<<<8192, 256, 0, stream>>>(xz, conv_w + i * 8192, conv_b + i * 2048, u, u16);
      gemm16_k<<<8, 256, 0, stream>>>(u16, 2048, xw16 + (size_t)i * 196608, 2048,
                                      nullptr, nullptr, dbc, 96, dbc16, 8, 96, 2048);
      gemm16_k<<<128, 256, 0, stream>>>(dbc16, 96, dtw16 + (size_t)i * 131072, 64,
                                        nullptr, dt_b + i * 2048, dtv, 2048, nullptr, 8, 2048, 64);
      scan_p1f_k<<<dim3(128, NCH), 256, 0, stream>>>(dtv, u, dbc, A_log + i * 32768, Pg, qg);
      scan_p2_k<<<128, 256, 0, stream>>>(Pg, qg, hst);
      scan_p3f_k<<<dim3(128, NCH), 256, 0, stream>>>(dtv, u, dbc, xz, A_log + i * 32768,
                                                     D_par + i * 2048, hst, y16);
      gemm16_k<<<64, 256, 0, stream>>>(y16, 2048, oww16 + (size_t)i * 2097152, 2048,
                                       x, nullptr, x, 1024, nullptr, 8, 1024, 2048);
    }

    rmsnorm16_k<<<1024, 256, 0, stream>>>(x, normf, xnf16);
    gemm16_k<<<2000, 256, 0, stream>>>(xnf16, 1024, lmw16, 1024,
                                       nullptr, nullptr, out, 32000, nullptr, 8, 32000, 1024);
  } else {
    // fallback: round-1 proven path (f32 staging GEMM)
    float* xnf_f = (float*)d_ws;
    for (int i = 0; i < 4; ++i) {
      rmsnorm_k<<<1024, 256, 0, stream>>>(x, norm_w + i * 1024, xn_f);
      gemm_bt_k<<<dim3(8, 32), 256, 0, stream>>>(xn_f, 1024, in_w + (size_t)i * 4194304, 1024,
                                                 nullptr, xz, 4096, 4096, 1024);
      conv_silu_k<<<8192, 256, 0, stream>>>(xz, conv_w + i * 8192, conv_b + i * 2048, u, nullptr);
      gemm_bt_k<<<dim3(8, 1), 256, 0, stream>>>(u, 2048, x_w + (size_t)i * 196608, 2048,
                                                nullptr, dbc, 96, 96, 2048);
      gemm_bt_k<<<dim3(8, 16), 256, 0, stream>>>(dbc, 96, dt_w + (size_t)i * 131072, 64,
                                                 nullptr, dtv, 2048, 2048, 64);
      scan_p1_k<<<dim3(128, NCH), 256, 0, stream>>>(dtv, u, dbc, A_log + i * 32768,
                                                    dt_b + i * 2048, Pg, qg);
      scan_p2_k<<<128, 256, 0, stream>>>(Pg, qg, hst);
      scan_p3_k<<<dim3(128, NCH), 256, 0, stream>>>(dtv, u, dbc, xz, A_log + i * 32768,
                                                    D_par + i * 2048, dt_b + i * 2048, hst, y_f);
      gemm_bt_k<<<dim3(8, 8), 256, 0, stream>>>(y_f, 2048, out_w + (size_t)i * 2097152, 2048,
                                                x, x, 1024, 1024, 2048);
    }
    rmsnorm_k<<<1024, 256, 0, stream>>>(x, normf, xnf_f);
    gemm_bt_k<<<dim3(8, 250), 256, 0, stream>>>(xnf_f, 1024, lm_w, 1024,
                                                nullptr, out, 32000, 32000, 1024);
  }
}

// Round 4
// 1187.276 us; speedup vs baseline: 3.1285x; 1.0762x over previous
//
#include <hip/hip_runtime.h>
#include <hip/hip_bf16.h>
#include <math.h>

// Mamba forward, MI355X. B=1 L=1024 D=1024 DI=2048 S=16 R=64 DC=4 NL=4 VOCAB=32000
// Round 3: 2-phase double-buffered GEMM pipeline (counted vmcnt, raw barriers),
//          fused cvt / embed+rms0 / p2-into-p3. Fallback path unchanged.

typedef __attribute__((ext_vector_type(8))) short bf16x8;
typedef __attribute__((ext_vector_type(4))) float f32x4;

__device__ __forceinline__ short f2bf(float f) {
  union { float f; unsigned u; } v; v.f = f;
  unsigned u = v.u;
  unsigned r = (u + 0x7FFFu + ((u >> 16) & 1u)) >> 16;  // RNE
  return (short)r;
}

__device__ __forceinline__ bf16x8 pack8(float4 a, float4 b) {
  bf16x8 r;
  r[0] = f2bf(a.x); r[1] = f2bf(a.y); r[2] = f2bf(a.z); r[3] = f2bf(a.w);
  r[4] = f2bf(b.x); r[5] = f2bf(b.y); r[6] = f2bf(b.z); r[7] = f2bf(b.w);
  return r;
}

__device__ __forceinline__ float softplus_f(float x) {
  return (x > 20.f) ? x : log1pf(__expf(x));
}

__device__ __forceinline__ void gl_lds16(const void* g, void* l) {
  void* gnc = (void*)g;
  __builtin_amdgcn_global_load_lds((__attribute__((address_space(1))) void*)gnc,
                                   (__attribute__((address_space(3))) void*)l, 16, 0, 0);
}

// ---------------- fused f32 -> bf16 weight convert (5 regions) ----------------
__global__ __launch_bounds__(256) void cvt_all_k(const float* __restrict__ s0, unsigned short* __restrict__ d0, int n0,
                                                 const float* __restrict__ s1, unsigned short* __restrict__ d1, int n1,
                                                 const float* __restrict__ s2, unsigned short* __restrict__ d2, int n2,
                                                 const float* __restrict__ s3, unsigned short* __restrict__ d3, int n3,
                                                 const float* __restrict__ s4, unsigned short* __restrict__ d4, int n4) {
  int stride = gridDim.x * 256;
  int tot = n0 + n1 + n2 + n3 + n4;
  for (int i = blockIdx.x * 256 + threadIdx.x; i < tot; i += stride) {
    const float* s; unsigned short* d; int j = i;
    if (j < n0) { s = s0; d = d0; }
    else { j -= n0; if (j < n1) { s = s1; d = d1; }
      else { j -= n1; if (j < n2) { s = s2; d = d2; }
        else { j -= n2; if (j < n3) { s = s3; d = d3; }
          else { j -= n3; s = s4; d = d4; } } } }
    const float4* p = (const float4*)(s + (size_t)j * 8);
    float4 a = p[0], b = p[1];
    *(bf16x8*)(d + (size_t)j * 8) = pack8(a, b);
  }
}

// ---------------- embed + rmsnorm(layer0) fused ----------------
__global__ __launch_bounds__(256) void embed_rms_k(const int* __restrict__ tok,
                                                   const float* __restrict__ emb,
                                                   const float* __restrict__ w,
                                                   float* __restrict__ x,
                                                   unsigned short* __restrict__ xn16) {
  int l = blockIdx.x;
  int t = tok[l];
  float4 v = ((const float4*)(emb + (size_t)t * 1024))[threadIdx.x];
  ((float4*)(x + (size_t)l * 1024))[threadIdx.x] = v;
  float ss = v.x * v.x + v.y * v.y + v.z * v.z + v.w * v.w;
  ss += __shfl_down(ss, 32); ss += __shfl_down(ss, 16); ss += __shfl_down(ss, 8);
  ss += __shfl_down(ss, 4);  ss += __shfl_down(ss, 2);  ss += __shfl_down(ss, 1);
  __shared__ float wsum[4];
  if ((threadIdx.x & 63) == 0) wsum[threadIdx.x >> 6] = ss;
  __syncthreads();
  float tot = wsum[0] + wsum[1] + wsum[2] + wsum[3];
  float sc = rsqrtf(tot * (1.0f / 1024.0f) + 1e-5f);
  float4 wv = ((const float4*)w)[threadIdx.x];
  ushort4 o;
  o.x = (unsigned short)f2bf(v.x * sc * wv.x);
  o.y = (unsigned short)f2bf(v.y * sc * wv.y);
  o.z = (unsigned short)f2bf(v.z * sc * wv.z);
  o.w = (unsigned short)f2bf(v.w * sc * wv.w);
  *(ushort4*)(xn16 + (size_t)l * 1024 + threadIdx.x * 4) = o;
}

// ---------------- rmsnorm -> bf16 out ----------------
__global__ __launch_bounds__(256) void rmsnorm16_k(const float* __restrict__ x,
                                                   const float* __restrict__ w,
                                                   unsigned short* __restrict__ y) {
  int l = blockIdx.x;
  const float4* xr = (const float4*)(x + (size_t)l * 1024);
  float4 v = xr[threadIdx.x];
  float ss = v.x * v.x + v.y * v.y + v.z * v.z + v.w * v.w;
  ss += __shfl_down(ss, 32); ss += __shfl_down(ss, 16); ss += __shfl_down(ss, 8);
  ss += __shfl_down(ss, 4);  ss += __shfl_down(ss, 2);  ss += __shfl_down(ss, 1);
  __shared__ float wsum[4];
  if ((threadIdx.x & 63) == 0) wsum[threadIdx.x >> 6] = ss;
  __syncthreads();
  float tot = wsum[0] + wsum[1] + wsum[2] + wsum[3];
  float sc = rsqrtf(tot * (1.0f / 1024.0f) + 1e-5f);
  float4 wv = ((const float4*)w)[threadIdx.x];
  ushort4 o;
  o.x = (unsigned short)f2bf(v.x * sc * wv.x);
  o.y = (unsigned short)f2bf(v.y * sc * wv.y);
  o.z = (unsigned short)f2bf(v.z * sc * wv.z);
  o.w = (unsigned short)f2bf(v.w * sc * wv.w);
  *(ushort4*)(y + (size_t)l * 1024 + threadIdx.x * 4) = o;
}

// ---------------- rmsnorm f32 out (fallback) ----------------
__global__ __launch_bounds__(256) void rmsnorm_k(const float* __restrict__ x,
                                                 const float* __restrict__ w,
                                                 float* __restrict__ y) {
  int l = blockIdx.x;
  const float4* xr = (const float4*)(x + (size_t)l * 1024);
  float4 v = xr[threadIdx.x];
  float ss = v.x * v.x + v.y * v.y + v.z * v.z + v.w * v.w;
  ss += __shfl_down(ss, 32); ss += __shfl_down(ss, 16); ss += __shfl_down(ss, 8);
  ss += __shfl_down(ss, 4);  ss += __shfl_down(ss, 2);  ss += __shfl_down(ss, 1);
  __shared__ float wsum[4];
  if ((threadIdx.x & 63) == 0) wsum[threadIdx.x >> 6] = ss;
  __syncthreads();
  float tot = wsum[0] + wsum[1] + wsum[2] + wsum[3];
  float sc = rsqrtf(tot * (1.0f / 1024.0f) + 1e-5f);
  float4 wv = ((const float4*)w)[threadIdx.x];
  float4 o;
  o.x = v.x * sc * wv.x; o.y = v.y * sc * wv.y;
  o.z = v.z * sc * wv.z; o.w = v.w * sc * wv.w;
  ((float4*)(y + (size_t)l * 1024))[threadIdx.x] = o;
}

// ---------------- depthwise causal conv + bias + silu ----------------
__global__ __launch_bounds__(256) void conv_silu_k(const float* __restrict__ xz,
                                                   const float* __restrict__ cw,
                                                   const float* __restrict__ cb,
                                                   float* __restrict__ u,
                                                   unsigned short* __restrict__ u16) {
  int idx = blockIdx.x * 256 + threadIdx.x;   // l*2048 + d
  int d = idx & 2047;
  int l = idx >> 11;
  float acc = cb[d];
#pragma unroll
  for (int j = 0; j < 4; ++j) {
    int ll = l - 3 + j;
    if (ll >= 0) acc = fmaf(xz[(size_t)ll * 4096 + d], cw[d * 4 + j], acc);
  }
  float sig = 1.0f / (1.0f + __expf(-acc));
  float v = acc * sig;
  u[idx] = v;
  if (u16) u16[idx] = (unsigned short)f2bf(v);
}

// ============ bf16 GEMM, 2-phase double-buffered pipeline ============
// C[M,N] = A[M,K](bf16) @ W[N,K]^T(bf16). Tile 128x128, BK=64, 256 thr (2x2 waves).
// Counted vmcnt(8) + raw s_barrier: next tile's global_load_lds stay in flight
// across the acquire barrier; only one drain at the final K-step.
__global__ __launch_bounds__(256) void gemm16_k(const unsigned short* __restrict__ A, int lda,
                                                const unsigned short* __restrict__ W, int ldw,
                                                const float* __restrict__ addsrc,
                                                const float* __restrict__ spbias,
                                                float* __restrict__ C, int ldc,
                                                unsigned short* __restrict__ C16,
                                                int gx, int N, int K) {
  // bijective XCD-aware remap (m204)
  int total = gridDim.x;
  int lin = blockIdx.x;
  int q = total >> 3, r = total & 7;
  int xcd = lin & 7, idx = lin >> 3;
  int nl = (xcd < r ? xcd * (q + 1) : r * (q + 1) + (xcd - r) * q) + idx;
  const int bm = (nl % gx) << 7;
  const int bn = (nl / gx) << 7;

  const int tid = threadIdx.x;
  const int wid = tid >> 6;
  const int lane = tid & 63;
  const int wm = (wid >> 1) << 6;
  const int wn = (wid & 1) << 6;
  const int fr = lane & 15;
  const int kg = lane >> 4;
  const int srow = lane >> 3;   // 0..7
  const int sch  = lane & 7;    // 16B chunk 0..7
  const int xch  = sch ^ srow;  // pre-swizzled source chunk (read-side XOR matches)

  __shared__ unsigned short sA[2][8192];
  __shared__ unsigned short sB[2][8192];

  f32x4 acc[4][4];
#pragma unroll
  for (int i = 0; i < 4; ++i)
#pragma unroll
    for (int j = 0; j < 4; ++j) acc[i][j] = (f32x4){0.f, 0.f, 0.f, 0.f};

  // stage one K-tile (8 gl_lds per thread) into buffer b
  auto STAGE = [&](int b, int k0) {
#pragma unroll
    for (int t = 0; t < 4; ++t) {
      int g = (wid << 2) + t;          // 8-row group 0..15 (wave-uniform)
      int row = (g << 3) + srow;
      const unsigned short* ga = A + (size_t)(bm + row) * lda + k0 + (xch << 3);
      int wrow = bn + row; if (wrow >= N) wrow = N - 1;
      const unsigned short* gw = W + (size_t)wrow * ldw + k0 + (xch << 3);
      gl_lds16(ga, &sA[b][g << 9]);
      gl_lds16(gw, &sB[b][g << 9]);
    }
  };

  auto COMPUTE = [&](int b) {
#pragma unroll
    for (int ks = 0; ks < 2; ++ks) {
      bf16x8 af[4], bw[4];
#pragma unroll
      for (int mi = 0; mi < 4; ++mi) {
        int row = wm + (mi << 4) + fr;
        int xc = ((ks << 2) + kg) ^ (fr & 7);
        af[mi] = *(const bf16x8*)&sA[b][(row << 6) + (xc << 3)];
      }
#pragma unroll
      for (int ni = 0; ni < 4; ++ni) {
        int row = wn + (ni << 4) + fr;
        int xc = ((ks << 2) + kg) ^ (fr & 7);
        bw[ni] = *(const bf16x8*)&sB[b][(row << 6) + (xc << 3)];
      }
#pragma unroll
      for (int mi = 0; mi < 4; ++mi)
#pragma unroll
        for (int ni = 0; ni < 4; ++ni)
          acc[mi][ni] = __builtin_amdgcn_mfma_f32_16x16x32_bf16(af[mi], bw[ni], acc[mi][ni], 0, 0, 0);
    }
  };

  const int nt = K >> 6;
  STAGE(0, 0);
  int cur = 0;
  for (int t = 0; t + 1 < nt; ++t) {
    STAGE(cur ^ 1, (t + 1) << 6);                      // prefetch next tile (stays in flight)
    asm volatile("s_waitcnt vmcnt(8)" ::: "memory");   // oldest 8 (buf[cur]) landed
    __builtin_amdgcn_s_barrier();                      // acquire: all waves' cur data visible
    __builtin_amdgcn_sched_barrier(0);                 // pin ds_reads after barrier
    COMPUTE(cur);
    __builtin_amdgcn_s_barrier();                      // release: safe to overwrite cur next iter
    cur ^= 1;
  }
  asm volatile("s_waitcnt vmcnt(0)" ::: "memory");
  __builtin_amdgcn_s_barrier();
  __builtin_amdgcn_sched_barrier(0);
  COMPUTE(cur);

#pragma unroll
  for (int mi = 0; mi < 4; ++mi)
#pragma unroll
    for (int ni = 0; ni < 4; ++ni) {
      int n = bn + wn + (ni << 4) + fr;
      if (n < N) {
#pragma unroll
        for (int i = 0; i < 4; ++i) {
          int m = bm + wm + (mi << 4) + (kg << 2) + i;
          size_t off = (size_t)m * ldc + n;
          float v = acc[mi][ni][i];
          if (addsrc) v += addsrc[off];
          if (spbias) v = softplus_f(v + spbias[n]);
          C[off] = v;
          if (C16) C16[off] = (unsigned short)f2bf(v);
        }
      }
    }
}

// ---------------- f32 GEMM (fallback only) ----------------
__global__ __launch_bounds__(256) void gemm_bt_k(const float* __restrict__ A, int lda,
                                                 const float* __restrict__ W, int ldw,
                                                 const float* __restrict__ addsrc,
                                                 float* __restrict__ C, int ldc,
                                                 int N, int K) {
  const int tid  = threadIdx.x;
  const int srow = tid >> 1;
  const int skg  = (tid & 1) << 1;
  const int bm = blockIdx.x << 7;
  const int bn = blockIdx.y << 7;
  const int wid = tid >> 6;
  const int lane = tid & 63;
  const int wm = (wid >> 1) << 6;
  const int wn = (wid & 1) << 6;
  const int fr = lane & 15;
  const int kg = lane >> 4;

  __shared__ bf16x8 lA[4][128];
  __shared__ bf16x8 lB[4][128];

  f32x4 zero4 = {0.f, 0.f, 0.f, 0.f};
  f32x4 acc[4][4];
#pragma unroll
  for (int i = 0; i < 4; ++i)
#pragma unroll
    for (int j = 0; j < 4; ++j) acc[i][j] = zero4;

  const bool wvalid = (bn + srow) < N;
  const float* gA = A + (size_t)(bm + srow) * lda + (skg << 3);
  const float* gW = W + (size_t)(wvalid ? (bn + srow) : 0) * ldw + (skg << 3);

  for (int k0 = 0; k0 < K; k0 += 32) {
    float4 a0 = *(const float4*)(gA + k0);
    float4 a1 = *(const float4*)(gA + k0 + 4);
    float4 a2 = *(const float4*)(gA + k0 + 8);
    float4 a3 = *(const float4*)(gA + k0 + 12);
    float4 w0 = make_float4(0.f, 0.f, 0.f, 0.f), w1 = w0, w2 = w0, w3 = w0;
    if (wvalid) {
      w0 = *(const float4*)(gW + k0);
      w1 = *(const float4*)(gW + k0 + 4);
      w2 = *(const float4*)(gW + k0 + 8);
      w3 = *(const float4*)(gW + k0 + 12);
    }
    __syncthreads();
    lA[skg][srow]     = pack8(a0, a1);
    lA[skg + 1][srow] = pack8(a2, a3);
    lB[skg][srow]     = pack8(w0, w1);
    lB[skg + 1][srow] = pack8(w2, w3);
    __syncthreads();

    bf16x8 af[4], bf_[4];
#pragma unroll
    for (int mi = 0; mi < 4; ++mi) af[mi] = lA[kg][wm + (mi << 4) + fr];
#pragma unroll
    for (int ni = 0; ni < 4; ++ni) bf_[ni] = lB[kg][wn + (ni << 4) + fr];
#pragma unroll
    for (int mi = 0; mi < 4; ++mi)
#pragma unroll
      for (int ni = 0; ni < 4; ++ni)
        acc[mi][ni] = __builtin_amdgcn_mfma_f32_16x16x32_bf16(af[mi], bf_[ni], acc[mi][ni], 0, 0, 0);
  }

#pragma unroll
  for (int mi = 0; mi < 4; ++mi)
#pragma unroll
    for (int ni = 0; ni < 4; ++ni) {
      int n = bn + wn + (ni << 4) + fr;
      if (n < N) {
#pragma unroll
        for (int i = 0; i < 4; ++i) {
          int m = bm + wm + (mi << 4) + (kg << 2) + i;
          size_t off = (size_t)m * ldc + n;
          float v = acc[mi][ni][i];
          if (addsrc) v += addsrc[off];
          C[off] = v;
        }
      }
    }
}

// ---------------- chunk-parallel scan ----------------
#define NCH 32
#define CHL 32

// fast path: dtv already softplus'ed
__global__ __launch_bounds__(256) void scan_p1f_k(const float* __restrict__ dtv,
                                                  const float* __restrict__ u,
                                                  const float* __restrict__ dbc,
                                                  const float* __restrict__ A_log,
                                                  float* __restrict__ Pg,
                                                  float* __restrict__ qg) {
  int tid = threadIdx.x;
  int s = tid & 15, dg = tid >> 4;
  int d = (blockIdx.x << 4) + dg;
  int c = blockIdx.y;
  int l0 = c << 5;
  float A = -__expf(A_log[d * 16 + s]);
  float P = 1.f, q = 0.f;
#pragma unroll 4
  for (int i = 0; i < CHL; ++i) {
    int l = l0 + i;
    size_t rd = (size_t)l * 2048 + d;
    float dt = dtv[rd];
    float dA = __expf(dt * A);
    P *= dA;
    q = fmaf(dA, q, dt * u[rd] * dbc[l * 96 + 64 + s]);
  }
  size_t o = (size_t)c * 32768 + d * 16 + s;
  Pg[o] = P;
  qg[o] = q;
}

// p3 with p2 merged: each block computes its chunk-prefix from Pg/qg.
__global__ __launch_bounds__(256) void scan_p3f_k(const float* __restrict__ dtv,
                                                  const float* __restrict__ u,
                                                  const float* __restrict__ dbc,
                                                  const float* __restrict__ xz,
                                                  const float* __restrict__ A_log,
                                                  const float* __restrict__ Dp,
                                                  const float* __restrict__ Pg,
                                                  const float* __restrict__ qg,
                                                  unsigned short* __restrict__ y16) {
  int tid = threadIdx.x;
  int s = tid & 15, dg = tid >> 4;
  int d = (blockIdx.x << 4) + dg;
  int c = blockIdx.y;
  int l0 = c << 5;
  float A = -__expf(A_log[d * 16 + s]);
  float dpar = Dp[d];
  float h = 0.f;
  for (int cc = 0; cc < c; ++cc) {
    size_t o = (size_t)cc * 32768 + d * 16 + s;
    h = fmaf(Pg[o], h, qg[o]);
  }
#pragma unroll 4
  for (int i = 0; i < CHL; ++i) {
    int l = l0 + i;
    size_t rd = (size_t)l * 2048 + d;
    float dt = dtv[rd];
    float uv = u[rd];
    float dA = __expf(dt * A);
    h = fmaf(dA, h, dt * uv * dbc[l * 96 + 64 + s]);
    float p = h * dbc[l * 96 + 80 + s];
    p += __shfl_xor(p, 1); p += __shfl_xor(p, 2);
    p += __shfl_xor(p, 4); p += __shfl_xor(p, 8);
    if (s == 0) {
      float zv = xz[(size_t)l * 4096 + 2048 + d];
      float sig = 1.0f / (1.0f + __expf(-zv));
      y16[rd] = (unsigned short)f2bf((p + uv * dpar) * (zv * sig));
    }
  }
}

// fallback scan (softplus in-kernel, f32 y)
__global__ __launch_bounds__(256) void scan_p1_k(const float* __restrict__ dtr,
                                                 const float* __restrict__ u,
                                                 const float* __restrict__ dbc,
                                                 const float* __restrict__ A_log,
                                                 const float* __restrict__ dtb,
                                                 float* __restrict__ Pg,
                                                 float* __restrict__ qg) {
  int tid = threadIdx.x;
  int s = tid & 15, dg = tid >> 4;
  int d = (blockIdx.x << 4) + dg;
  int c = blockIdx.y;
  int l0 = c << 5;
  float A = -__expf(A_log[d * 16 + s]);
  float bias = dtb[d];
  float P = 1.f, q = 0.f;
#pragma unroll 4
  for (int i = 0; i < CHL; ++i) {
    int l = l0 + i;
    float dt = softplus_f(dtr[(size_t)l * 2048 + d] + bias);
    float dA = __expf(dt * A);
    P *= dA;
    q = fmaf(dA, q, dt * u[(size_t)l * 2048 + d] * dbc[l * 96 + 64 + s]);
  }
  size_t o = (size_t)c * 32768 + d * 16 + s;
  Pg[o] = P;
  qg[o] = q;
}

__global__ __launch_bounds__(256) void scan_p2_k(const float* __restrict__ Pg,
                                                 const float* __restrict__ qg,
                                                 float* __restrict__ hst) {
  int idx = blockIdx.x * 256 + threadIdx.x;
  float h = 0.f;
#pragma unroll
  for (int c = 0; c < NCH; ++c) {
    size_t o = (size_t)c * 32768 + idx;
    hst[o] = h;
    h = fmaf(Pg[o], h, qg[o]);
  }
}

__global__ __launch_bounds__(256) void scan_p3_k(const float* __restrict__ dtr,
                                                 const float* __restrict__ u,
                                                 const float* __restrict__ dbc,
                                                 const float* __restrict__ xz,
                                                 const float* __restrict__ A_log,
                                                 const float* __restrict__ Dp,
                                                 const float* __restrict__ dtb,
                                                 const float* __restrict__ hst,
                                                 float* __restrict__ y) {
  int tid = threadIdx.x;
  int s = tid & 15, dg = tid >> 4;
  int d = (blockIdx.x << 4) + dg;
  int c = blockIdx.y;
  int l0 = c << 5;
  float A = -__expf(A_log[d * 16 + s]);
  float dpar = Dp[d];
  float bias = dtb[d];
  float h = hst[(size_t)c * 32768 + d * 16 + s];
#pragma unroll 4
  for (int i = 0; i < CHL; ++i) {
    int l = l0 + i;
    size_t rd = (size_t)l * 2048 + d;
    float dt = softplus_f(dtr[rd] + bias);
    float uv = u[rd];
    float dA = __expf(dt * A);
    h = fmaf(dA, h, dt * uv * dbc[l * 96 + 64 + s]);
    float p = h * dbc[l * 96 + 80 + s];
    p += __shfl_xor(p, 1); p += __shfl_xor(p, 2);
    p += __shfl_xor(p, 4); p += __shfl_xor(p, 8);
    if (s == 0) {
      float zv = xz[(size_t)l * 4096 + 2048 + d];
      float sig = 1.0f / (1.0f + __expf(-zv));
      y[rd] = (p + uv * dpar) * (zv * sig);
    }
  }
}

// ---------------- host launch ----------------
extern "C" void kernel_launch(void* const* d_in, const int* in_sizes, int n_in,
                              void* d_out, int out_size, void* d_ws, size_t ws_size,
                              hipStream_t stream) {
  const int*   tokens = (const int*)d_in[0];
  const float* embed  = (const float*)d_in[1];
  const float* norm_w = (const float*)d_in[2];
  const float* in_w   = (const float*)d_in[3];
  const float* conv_w = (const float*)d_in[4];
  const float* conv_b = (const float*)d_in[5];
  const float* x_w    = (const float*)d_in[6];
  const float* dt_w   = (const float*)d_in[7];
  const float* dt_b   = (const float*)d_in[8];
  const float* A_log  = (const float*)d_in[9];
  const float* D_par  = (const float*)d_in[10];
  const float* out_w  = (const float*)d_in[11];
  const float* normf  = (const float*)d_in[12];
  const float* lm_w   = (const float*)d_in[13];

  float* out = (float*)d_out;
  // f32 scratch in d_out (dead before lm_head writes it)
  float* x    = out;                    // 1M
  float* xz   = x    + 1024 * 1024;    // 4M
  float* u    = xz   + 1024 * 4096;    // 2M
  float* dtv  = u    + 1024 * 2048;    // 2M (fast: softplus'ed; fallback: raw dt)
  float* dbc  = dtv  + 1024 * 2048;    // 96K
  float* Pg   = dbc  + 1024 * 96;      // 1M
  float* qg   = Pg   + 32 * 32768;     // 1M
  float* hst  = qg   + 32 * 32768;     // 1M (fallback)
  float* xn_f = hst  + 32 * 32768;     // 1M (fallback)
  float* y_f  = xn_f + 1024 * 1024;    // 2M (fallback)
  unsigned short* xn16  = (unsigned short*)(y_f + 1024 * 2048);
  unsigned short* u16   = xn16 + 1024 * 1024;
  unsigned short* y16   = u16  + 1024 * 2048;
  unsigned short* dbc16 = y16  + 1024 * 2048;   // ends ~70.8 MB < 131 MB

  // d_ws: bf16 weights + xnf
  unsigned short* inw16 = (unsigned short*)d_ws;      // 16,777,216
  unsigned short* oww16 = inw16 + 16777216;           //  8,388,608
  unsigned short* xw16  = oww16 + 8388608;            //    786,432
  unsigned short* dtw16 = xw16  + 786432;             //    524,288
  unsigned short* lmw16 = dtw16 + 524288;             // 32,768,000
  unsigned short* xnf16 = lmw16 + 32768000;           //  1,048,576
  const size_t need = (size_t)(16777216 + 8388608 + 786432 + 524288 + 32768000 + 1048576) * 2;
  const bool fast = ws_size >= need;

  if (fast) {
    cvt_all_k<<<4096, 256, 0, stream>>>(in_w, inw16, 2097152,
                                        out_w, oww16, 1048576,
                                        x_w, xw16, 98304,
                                        dt_w, dtw16, 65536,
                                        lm_w, lmw16, 4096000);
    embed_rms_k<<<1024, 256, 0, stream>>>(tokens, embed, norm_w, x, xn16);

    for (int i = 0; i < 4; ++i) {
      if (i > 0) rmsnorm16_k<<<1024, 256, 0, stream>>>(x, norm_w + i * 1024, xn16);
      gemm16_k<<<256, 256, 0, stream>>>(xn16, 1024, inw16 + (size_t)i * 4194304, 1024,
                                        nullptr, nullptr, xz, 4096, nullptr, 8, 4096, 1024);
      conv_silu_k<<<8192, 256, 0, stream>>>(xz, conv_w + i * 8192, conv_b + i * 2048, u, u16);
      gemm16_k<<<8, 256, 0, stream>>>(u16, 2048, xw16 + (size_t)i * 196608, 2048,
                                      nullptr, nullptr, dbc, 96, dbc16, 8, 96, 2048);
      gemm16_k<<<128, 256, 0, stream>>>(dbc16, 96, dtw16 + (size_t)i * 131072, 64,
                                        nullptr, dt_b + i * 2048, dtv, 2048, nullptr, 8, 2048, 64);
      scan_p1f_k<<<dim3(128, NCH), 256, 0, stream>>>(dtv, u, dbc, A_log + i * 32768, Pg, qg);
      scan_p3f_k<<<dim3(128, NCH), 256, 0, stream>>>(dtv, u, dbc, xz, A_log + i * 32768,
                                                     D_par + i * 2048, Pg, qg, y16);
      gemm16_k<<<64, 256, 0, stream>>>(y16, 2048, oww16 + (size_t)i * 2097152, 2048,
                                       x, nullptr, x, 1024, nullptr, 8, 1024, 2048);
    }

    rmsnorm16_k<<<1024, 256, 0, stream>>>(x, normf, xnf16);
    gemm16_k<<<2000, 256, 0, stream>>>(xnf16, 1024, lmw16, 1024,
                                       nullptr, nullptr, out, 32000, nullptr, 8, 32000, 1024);
  } else {
    // fallback: round-1 proven path (f32 staging GEMM)
    float* xnf_f = (float*)d_ws;
    __global__ void (*ek)(const int*, const float*, float*);
    // embed
    // (reuse embed via embed_rms? fallback keeps separate simple path)
    embed_rms_k<<<1024, 256, 0, stream>>>(tokens, embed, norm_w, x, xn16);  // xn16 unused downstream
    for (int i = 0; i < 4; ++i) {
      rmsnorm_k<<<1024, 256, 0, stream>>>(x, norm_w + i * 1024, xn_f);
      gemm_bt_k<<<dim3(8, 32), 256, 0, stream>>>(xn_f, 1024, in_w + (size_t)i * 4194304, 1024,
                                                 nullptr, xz, 4096, 4096, 1024);
      conv_silu_k<<<8192, 256, 0, stream>>>(xz, conv_w + i * 8192, conv_b + i * 2048, u, nullptr);
      gemm_bt_k<<<dim3(8, 1), 256, 0, stream>>>(u, 2048, x_w + (size_t)i * 196608, 2048,
                                                nullptr, dbc, 96, 96, 2048);
      gemm_bt_k<<<dim3(8, 16), 256, 0, stream>>>(dbc, 96, dt_w + (size_t)i * 131072, 64,
                                                 nullptr, dtv, 2048, 2048, 64);
      scan_p1_k<<<dim3(128, NCH), 256, 0, stream>>>(dtv, u, dbc, A_log + i * 32768,
                                                    dt_b + i * 2048, Pg, qg);
      scan_p2_k<<<128, 256, 0, stream>>>(Pg, qg, hst);
      scan_p3_k<<<dim3(128, NCH), 256, 0, stream>>>(dtv, u, dbc, xz, A_log + i * 32768,
                                                    D_par + i * 2048, dt_b + i * 2048, hst, y_f);
      gemm_bt_k<<<dim3(8, 8), 256, 0, stream>>>(y_f, 2048, out_w + (size_t)i * 2097152, 2048,
                                                x, x, 1024, 1024, 2048);
    }
    rmsnorm_k<<<1024, 256, 0, stream>>>(x, normf, xnf_f);
    gemm_bt_k<<<dim3(8, 250), 256, 0, stream>>>(xnf_f, 1024, lm_w, 1024,
                                                nullptr, out, 32000, 32000, 1024);
  }
}

// Round 5
// 945.974 us; speedup vs baseline: 3.9266x; 1.2551x over previous
//
#include <hip/hip_runtime.h>
#include <hip/hip_bf16.h>
#include <math.h>

// Mamba forward, MI355X. B=1 L=1024 D=1024 DI=2048 S=16 R=64 DC=4 NL=4 VOCAB=32000
// Round 5: lm_head on 256x256 8-wave tile (2-phase counted vmcnt, 128KB LDS dbuf);
//          split-K x4 for x_proj/out_proj; rest as round 4.

typedef __attribute__((ext_vector_type(8))) short bf16x8;
typedef __attribute__((ext_vector_type(4))) float f32x4;

__device__ __forceinline__ short f2bf(float f) {
  union { float f; unsigned u; } v; v.f = f;
  unsigned u = v.u;
  unsigned r = (u + 0x7FFFu + ((u >> 16) & 1u)) >> 16;  // RNE
  return (short)r;
}

__device__ __forceinline__ bf16x8 pack8(float4 a, float4 b) {
  bf16x8 r;
  r[0] = f2bf(a.x); r[1] = f2bf(a.y); r[2] = f2bf(a.z); r[3] = f2bf(a.w);
  r[4] = f2bf(b.x); r[5] = f2bf(b.y); r[6] = f2bf(b.z); r[7] = f2bf(b.w);
  return r;
}

__device__ __forceinline__ float softplus_f(float x) {
  return (x > 20.f) ? x : log1pf(__expf(x));
}

__device__ __forceinline__ void gl_lds16(const void* g, void* l) {
  void* gnc = (void*)g;
  __builtin_amdgcn_global_load_lds((__attribute__((address_space(1))) void*)gnc,
                                   (__attribute__((address_space(3))) void*)l, 16, 0, 0);
}

// ---------------- fused f32 -> bf16 weight convert (5 regions) ----------------
__global__ __launch_bounds__(256) void cvt_all_k(const float* __restrict__ s0, unsigned short* __restrict__ d0, int n0,
                                                 const float* __restrict__ s1, unsigned short* __restrict__ d1, int n1,
                                                 const float* __restrict__ s2, unsigned short* __restrict__ d2, int n2,
                                                 const float* __restrict__ s3, unsigned short* __restrict__ d3, int n3,
                                                 const float* __restrict__ s4, unsigned short* __restrict__ d4, int n4) {
  int stride = gridDim.x * 256;
  int tot = n0 + n1 + n2 + n3 + n4;
  for (int i = blockIdx.x * 256 + threadIdx.x; i < tot; i += stride) {
    const float* s; unsigned short* d; int j = i;
    if (j < n0) { s = s0; d = d0; }
    else { j -= n0; if (j < n1) { s = s1; d = d1; }
      else { j -= n1; if (j < n2) { s = s2; d = d2; }
        else { j -= n2; if (j < n3) { s = s3; d = d3; }
          else { j -= n3; s = s4; d = d4; } } } }
    const float4* p = (const float4*)(s + (size_t)j * 8);
    float4 a = p[0], b = p[1];
    *(bf16x8*)(d + (size_t)j * 8) = pack8(a, b);
  }
}

// ---------------- embed + rmsnorm(layer0) fused ----------------
__global__ __launch_bounds__(256) void embed_rms_k(const int* __restrict__ tok,
                                                   const float* __restrict__ emb,
                                                   const float* __restrict__ w,
                                                   float* __restrict__ x,
                                                   unsigned short* __restrict__ xn16) {
  int l = blockIdx.x;
  int t = tok[l];
  float4 v = ((const float4*)(emb + (size_t)t * 1024))[threadIdx.x];
  ((float4*)(x + (size_t)l * 1024))[threadIdx.x] = v;
  float ss = v.x * v.x + v.y * v.y + v.z * v.z + v.w * v.w;
  ss += __shfl_down(ss, 32); ss += __shfl_down(ss, 16); ss += __shfl_down(ss, 8);
  ss += __shfl_down(ss, 4);  ss += __shfl_down(ss, 2);  ss += __shfl_down(ss, 1);
  __shared__ float wsum[4];
  if ((threadIdx.x & 63) == 0) wsum[threadIdx.x >> 6] = ss;
  __syncthreads();
  float tot = wsum[0] + wsum[1] + wsum[2] + wsum[3];
  float sc = rsqrtf(tot * (1.0f / 1024.0f) + 1e-5f);
  float4 wv = ((const float4*)w)[threadIdx.x];
  ushort4 o;
  o.x = (unsigned short)f2bf(v.x * sc * wv.x);
  o.y = (unsigned short)f2bf(v.y * sc * wv.y);
  o.z = (unsigned short)f2bf(v.z * sc * wv.z);
  o.w = (unsigned short)f2bf(v.w * sc * wv.w);
  *(ushort4*)(xn16 + (size_t)l * 1024 + threadIdx.x * 4) = o;
}

// ---------------- rmsnorm -> bf16 out ----------------
__global__ __launch_bounds__(256) void rmsnorm16_k(const float* __restrict__ x,
                                                   const float* __restrict__ w,
                                                   unsigned short* __restrict__ y) {
  int l = blockIdx.x;
  const float4* xr = (const float4*)(x + (size_t)l * 1024);
  float4 v = xr[threadIdx.x];
  float ss = v.x * v.x + v.y * v.y + v.z * v.z + v.w * v.w;
  ss += __shfl_down(ss, 32); ss += __shfl_down(ss, 16); ss += __shfl_down(ss, 8);
  ss += __shfl_down(ss, 4);  ss += __shfl_down(ss, 2);  ss += __shfl_down(ss, 1);
  __shared__ float wsum[4];
  if ((threadIdx.x & 63) == 0) wsum[threadIdx.x >> 6] = ss;
  __syncthreads();
  float tot = wsum[0] + wsum[1] + wsum[2] + wsum[3];
  float sc = rsqrtf(tot * (1.0f / 1024.0f) + 1e-5f);
  float4 wv = ((const float4*)w)[threadIdx.x];
  ushort4 o;
  o.x = (unsigned short)f2bf(v.x * sc * wv.x);
  o.y = (unsigned short)f2bf(v.y * sc * wv.y);
  o.z = (unsigned short)f2bf(v.z * sc * wv.z);
  o.w = (unsigned short)f2bf(v.w * sc * wv.w);
  *(ushort4*)(y + (size_t)l * 1024 + threadIdx.x * 4) = o;
}

// ---------------- rmsnorm f32 out (fallback) ----------------
__global__ __launch_bounds__(256) void rmsnorm_k(const float* __restrict__ x,
                                                 const float* __restrict__ w,
                                                 float* __restrict__ y) {
  int l = blockIdx.x;
  const float4* xr = (const float4*)(x + (size_t)l * 1024);
  float4 v = xr[threadIdx.x];
  float ss = v.x * v.x + v.y * v.y + v.z * v.z + v.w * v.w;
  ss += __shfl_down(ss, 32); ss += __shfl_down(ss, 16); ss += __shfl_down(ss, 8);
  ss += __shfl_down(ss, 4);  ss += __shfl_down(ss, 2);  ss += __shfl_down(ss, 1);
  __shared__ float wsum[4];
  if ((threadIdx.x & 63) == 0) wsum[threadIdx.x >> 6] = ss;
  __syncthreads();
  float tot = wsum[0] + wsum[1] + wsum[2] + wsum[3];
  float sc = rsqrtf(tot * (1.0f / 1024.0f) + 1e-5f);
  float4 wv = ((const float4*)w)[threadIdx.x];
  float4 o;
  o.x = v.x * sc * wv.x; o.y = v.y * sc * wv.y;
  o.z = v.z * sc * wv.z; o.w = v.w * sc * wv.w;
  ((float4*)(y + (size_t)l * 1024))[threadIdx.x] = o;
}

// ---------------- depthwise causal conv + bias + silu ----------------
__global__ __launch_bounds__(256) void conv_silu_k(const float* __restrict__ xz,
                                                   const float* __restrict__ cw,
                                                   const float* __restrict__ cb,
                                                   float* __restrict__ u,
                                                   unsigned short* __restrict__ u16) {
  int idx = blockIdx.x * 256 + threadIdx.x;   // l*2048 + d
  int d = idx & 2047;
  int l = idx >> 11;
  float acc = cb[d];
#pragma unroll
  for (int j = 0; j < 4; ++j) {
    int ll = l - 3 + j;
    if (ll >= 0) acc = fmaf(xz[(size_t)ll * 4096 + d], cw[d * 4 + j], acc);
  }
  float sig = 1.0f / (1.0f + __expf(-acc));
  float v = acc * sig;
  u[idx] = v;
  if (u16) u16[idx] = (unsigned short)f2bf(v);
}

// ============ bf16 GEMM 128x128, 2-phase double-buffered (proven r3/r4) ============
__global__ __launch_bounds__(256) void gemm16_k(const unsigned short* __restrict__ A, int lda,
                                                const unsigned short* __restrict__ W, int ldw,
                                                const float* __restrict__ addsrc,
                                                const float* __restrict__ spbias,
                                                float* __restrict__ C, int ldc,
                                                unsigned short* __restrict__ C16,
                                                int gx, int N, int K) {
  int total = gridDim.x;
  int lin = blockIdx.x;
  int q = total >> 3, r = total & 7;
  int xcd = lin & 7, idx = lin >> 3;
  int nl = (xcd < r ? xcd * (q + 1) : r * (q + 1) + (xcd - r) * q) + idx;
  const int bm = (nl % gx) << 7;
  const int bn = (nl / gx) << 7;

  const int tid = threadIdx.x;
  const int wid = tid >> 6;
  const int lane = tid & 63;
  const int wm = (wid >> 1) << 6;
  const int wn = (wid & 1) << 6;
  const int fr = lane & 15;
  const int kg = lane >> 4;
  const int srow = lane >> 3;
  const int sch  = lane & 7;
  const int xch  = sch ^ srow;

  __shared__ unsigned short sA[2][8192];
  __shared__ unsigned short sB[2][8192];

  f32x4 acc[4][4];
#pragma unroll
  for (int i = 0; i < 4; ++i)
#pragma unroll
    for (int j = 0; j < 4; ++j) acc[i][j] = (f32x4){0.f, 0.f, 0.f, 0.f};

  auto STAGE = [&](int b, int k0) {
#pragma unroll
    for (int t = 0; t < 4; ++t) {
      int g = (wid << 2) + t;
      int row = (g << 3) + srow;
      const unsigned short* ga = A + (size_t)(bm + row) * lda + k0 + (xch << 3);
      int wrow = bn + row; if (wrow >= N) wrow = N - 1;
      const unsigned short* gw = W + (size_t)wrow * ldw + k0 + (xch << 3);
      gl_lds16(ga, &sA[b][g << 9]);
      gl_lds16(gw, &sB[b][g << 9]);
    }
  };

  auto COMPUTE = [&](int b) {
#pragma unroll
    for (int ks = 0; ks < 2; ++ks) {
      bf16x8 af[4], bw[4];
#pragma unroll
      for (int mi = 0; mi < 4; ++mi) {
        int row = wm + (mi << 4) + fr;
        int xc = ((ks << 2) + kg) ^ (fr & 7);
        af[mi] = *(const bf16x8*)&sA[b][(row << 6) + (xc << 3)];
      }
#pragma unroll
      for (int ni = 0; ni < 4; ++ni) {
        int row = wn + (ni << 4) + fr;
        int xc = ((ks << 2) + kg) ^ (fr & 7);
        bw[ni] = *(const bf16x8*)&sB[b][(row << 6) + (xc << 3)];
      }
#pragma unroll
      for (int mi = 0; mi < 4; ++mi)
#pragma unroll
        for (int ni = 0; ni < 4; ++ni)
          acc[mi][ni] = __builtin_amdgcn_mfma_f32_16x16x32_bf16(af[mi], bw[ni], acc[mi][ni], 0, 0, 0);
    }
  };

  const int nt = K >> 6;
  STAGE(0, 0);
  int cur = 0;
  for (int t = 0; t + 1 < nt; ++t) {
    STAGE(cur ^ 1, (t + 1) << 6);
    asm volatile("s_waitcnt vmcnt(8)" ::: "memory");
    __builtin_amdgcn_s_barrier();
    __builtin_amdgcn_sched_barrier(0);
    COMPUTE(cur);
    __builtin_amdgcn_s_barrier();
    cur ^= 1;
  }
  asm volatile("s_waitcnt vmcnt(0)" ::: "memory");
  __builtin_amdgcn_s_barrier();
  __builtin_amdgcn_sched_barrier(0);
  COMPUTE(cur);

#pragma unroll
  for (int mi = 0; mi < 4; ++mi)
#pragma unroll
    for (int ni = 0; ni < 4; ++ni) {
      int n = bn + wn + (ni << 4) + fr;
      if (n < N) {
#pragma unroll
        for (int i = 0; i < 4; ++i) {
          int m = bm + wm + (mi << 4) + (kg << 2) + i;
          size_t off = (size_t)m * ldc + n;
          float v = acc[mi][ni][i];
          if (addsrc) v += addsrc[off];
          if (spbias) v = softplus_f(v + spbias[n]);
          C[off] = v;
          if (C16) C16[off] = (unsigned short)f2bf(v);
        }
      }
    }
}

// ============ split-K variant of the 128x128 GEMM: partials, no epilogue ============
// grid (blocks, nsplit); partial s at Cp + s*Mtot*ldc.
__global__ __launch_bounds__(256) void gemm16sk_k(const unsigned short* __restrict__ A, int lda,
                                                  const unsigned short* __restrict__ W, int ldw,
                                                  float* __restrict__ Cp, int ldc,
                                                  int gx, int N, int Kchunk, int Mtot) {
  int total = gridDim.x;
  int lin = blockIdx.x;
  int q = total >> 3, r = total & 7;
  int xcd = lin & 7, idx = lin >> 3;
  int nl = (xcd < r ? xcd * (q + 1) : r * (q + 1) + (xcd - r) * q) + idx;
  const int bm = (nl % gx) << 7;
  const int bn = (nl / gx) << 7;
  const int ksplit = blockIdx.y;
  const int kbase = ksplit * Kchunk;

  const int tid = threadIdx.x;
  const int wid = tid >> 6;
  const int lane = tid & 63;
  const int wm = (wid >> 1) << 6;
  const int wn = (wid & 1) << 6;
  const int fr = lane & 15;
  const int kg = lane >> 4;
  const int srow = lane >> 3;
  const int sch  = lane & 7;
  const int xch  = sch ^ srow;

  __shared__ unsigned short sA[2][8192];
  __shared__ unsigned short sB[2][8192];

  f32x4 acc[4][4];
#pragma unroll
  for (int i = 0; i < 4; ++i)
#pragma unroll
    for (int j = 0; j < 4; ++j) acc[i][j] = (f32x4){0.f, 0.f, 0.f, 0.f};

  auto STAGE = [&](int b, int k0) {
#pragma unroll
    for (int t = 0; t < 4; ++t) {
      int g = (wid << 2) + t;
      int row = (g << 3) + srow;
      const unsigned short* ga = A + (size_t)(bm + row) * lda + k0 + (xch << 3);
      int wrow = bn + row; if (wrow >= N) wrow = N - 1;
      const unsigned short* gw = W + (size_t)wrow * ldw + k0 + (xch << 3);
      gl_lds16(ga, &sA[b][g << 9]);
      gl_lds16(gw, &sB[b][g << 9]);
    }
  };

  auto COMPUTE = [&](int b) {
#pragma unroll
    for (int ks = 0; ks < 2; ++ks) {
      bf16x8 af[4], bw[4];
#pragma unroll
      for (int mi = 0; mi < 4; ++mi) {
        int row = wm + (mi << 4) + fr;
        int xc = ((ks << 2) + kg) ^ (fr & 7);
        af[mi] = *(const bf16x8*)&sA[b][(row << 6) + (xc << 3)];
      }
#pragma unroll
      for (int ni = 0; ni < 4; ++ni) {
        int row = wn + (ni << 4) + fr;
        int xc = ((ks << 2) + kg) ^ (fr & 7);
        bw[ni] = *(const bf16x8*)&sB[b][(row << 6) + (xc << 3)];
      }
#pragma unroll
      for (int mi = 0; mi < 4; ++mi)
#pragma unroll
        for (int ni = 0; ni < 4; ++ni)
          acc[mi][ni] = __builtin_amdgcn_mfma_f32_16x16x32_bf16(af[mi], bw[ni], acc[mi][ni], 0, 0, 0);
    }
  };

  const int nt = Kchunk >> 6;
  STAGE(0, kbase);
  int cur = 0;
  for (int t = 0; t + 1 < nt; ++t) {
    STAGE(cur ^ 1, kbase + ((t + 1) << 6));
    asm volatile("s_waitcnt vmcnt(8)" ::: "memory");
    __builtin_amdgcn_s_barrier();
    __builtin_amdgcn_sched_barrier(0);
    COMPUTE(cur);
    __builtin_amdgcn_s_barrier();
    cur ^= 1;
  }
  asm volatile("s_waitcnt vmcnt(0)" ::: "memory");
  __builtin_amdgcn_s_barrier();
  __builtin_amdgcn_sched_barrier(0);
  COMPUTE(cur);

  float* Cs = Cp + (size_t)ksplit * Mtot * ldc;
#pragma unroll
  for (int mi = 0; mi < 4; ++mi)
#pragma unroll
    for (int ni = 0; ni < 4; ++ni) {
      int n = bn + wn + (ni << 4) + fr;
      if (n < N) {
#pragma unroll
        for (int i = 0; i < 4; ++i) {
          int m = bm + wm + (mi << 4) + (kg << 2) + i;
          Cs[(size_t)m * ldc + n] = acc[mi][ni][i];
        }
      }
    }
}

// reduce x_proj partials -> dbc (f32) + dbc16
__global__ __launch_bounds__(256) void reduce_xp_k(const float* __restrict__ Cp,
                                                   float* __restrict__ dbc,
                                                   unsigned short* __restrict__ dbc16) {
  int i = blockIdx.x * 256 + threadIdx.x;   // 0..98303
  float v = Cp[i] + Cp[98304 + i] + Cp[2 * 98304 + i] + Cp[3 * 98304 + i];
  dbc[i] = v;
  dbc16[i] = (unsigned short)f2bf(v);
}

// reduce out_proj partials + residual (in-place on x)
__global__ __launch_bounds__(256) void reduce_op_k(const float* __restrict__ Cp,
                                                   float* __restrict__ x) {
  int i = blockIdx.x * 256 + threadIdx.x;   // float4 index, 0..262143
  const float4* p0 = (const float4*)Cp;
  const float4* p1 = (const float4*)(Cp + 1048576);
  const float4* p2 = (const float4*)(Cp + 2097152);
  const float4* p3 = (const float4*)(Cp + 3145728);
  float4 a = p0[i], b = p1[i], c = p2[i], d = p3[i];
  float4 xv = ((float4*)x)[i];
  xv.x += a.x + b.x + c.x + d.x;
  xv.y += a.y + b.y + c.y + d.y;
  xv.z += a.z + b.z + c.z + d.z;
  xv.w += a.w + b.w + c.w + d.w;
  ((float4*)x)[i] = xv;
}

// ============ bf16 GEMM 256x256, 8 waves, 2-phase counted vmcnt (lm_head) ============
// Per-wave output 128x64 (wr=wid>>2, wc=wid&3). LDS 128KB dbuf. N must allow full tiles
// via clamp; M multiple of 256.
__global__ __launch_bounds__(512, 2) void gemm256_k(const unsigned short* __restrict__ A, int lda,
                                                    const unsigned short* __restrict__ W, int ldw,
                                                    float* __restrict__ C, int ldc,
                                                    int gx, int N, int K) {
  int total = gridDim.x;
  int lin = blockIdx.x;
  int q = total >> 3, r = total & 7;
  int xcd = lin & 7, idx = lin >> 3;
  int nl = (xcd < r ? xcd * (q + 1) : r * (q + 1) + (xcd - r) * q) + idx;
  const int bm = (nl % gx) << 8;
  const int bn = (nl / gx) << 8;

  const int tid = threadIdx.x;
  const int wid = tid >> 6;       // 0..7
  const int lane = tid & 63;
  const int wm = (wid >> 2) << 7; // 0 or 128
  const int wn = (wid & 3) << 6;  // 0,64,128,192
  const int fr = lane & 15;
  const int kg = lane >> 4;
  const int srow = lane >> 3;     // 0..7
  const int sch  = lane & 7;      // 16B chunk
  const int xch  = sch ^ srow;

  __shared__ unsigned short sA[2][16384];
  __shared__ unsigned short sB[2][16384];

  f32x4 acc[8][4];
#pragma unroll
  for (int i = 0; i < 8; ++i)
#pragma unroll
    for (int j = 0; j < 4; ++j) acc[i][j] = (f32x4){0.f, 0.f, 0.f, 0.f};

  auto STAGE = [&](int b, int k0) {
#pragma unroll
    for (int t = 0; t < 4; ++t) {
      int g = (wid << 2) + t;          // 0..31
      int row = (g << 3) + srow;       // 0..255
      const unsigned short* ga = A + (size_t)(bm + row) * lda + k0 + (xch << 3);
      int wrow = bn + row; if (wrow >= N) wrow = N - 1;
      const unsigned short* gw = W + (size_t)wrow * ldw + k0 + (xch << 3);
      gl_lds16(ga, &sA[b][g << 9]);
      gl_lds16(gw, &sB[b][g << 9]);
    }
  };

  auto COMPUTE = [&](int b) {
#pragma unroll
    for (int ks = 0; ks < 2; ++ks) {
      bf16x8 af[8], bw[4];
#pragma unroll
      for (int mi = 0; mi < 8; ++mi) {
        int row = wm + (mi << 4) + fr;
        int xc = ((ks << 2) + kg) ^ (fr & 7);
        af[mi] = *(const bf16x8*)&sA[b][(row << 6) + (xc << 3)];
      }
#pragma unroll
      for (int ni = 0; ni < 4; ++ni) {
        int row = wn + (ni << 4) + fr;
        int xc = ((ks << 2) + kg) ^ (fr & 7);
        bw[ni] = *(const bf16x8*)&sB[b][(row << 6) + (xc << 3)];
      }
#pragma unroll
      for (int mi = 0; mi < 8; ++mi)
#pragma unroll
        for (int ni = 0; ni < 4; ++ni)
          acc[mi][ni] = __builtin_amdgcn_mfma_f32_16x16x32_bf16(af[mi], bw[ni], acc[mi][ni], 0, 0, 0);
    }
  };

  const int nt = K >> 6;
  STAGE(0, 0);
  int cur = 0;
  for (int t = 0; t + 1 < nt; ++t) {
    STAGE(cur ^ 1, (t + 1) << 6);
    asm volatile("s_waitcnt vmcnt(8)" ::: "memory");
    __builtin_amdgcn_s_barrier();
    __builtin_amdgcn_sched_barrier(0);
    COMPUTE(cur);
    __builtin_amdgcn_s_barrier();
    cur ^= 1;
  }
  asm volatile("s_waitcnt vmcnt(0)" ::: "memory");
  __builtin_amdgcn_s_barrier();
  __builtin_amdgcn_sched_barrier(0);
  COMPUTE(cur);

#pragma unroll
  for (int mi = 0; mi < 8; ++mi)
#pragma unroll
    for (int ni = 0; ni < 4; ++ni) {
      int n = bn + wn + (ni << 4) + fr;
      if (n < N) {
#pragma unroll
        for (int i = 0; i < 4; ++i) {
          int m = bm + wm + (mi << 4) + (kg << 2) + i;
          C[(size_t)m * ldc + n] = acc[mi][ni][i];
        }
      }
    }
}

// ---------------- f32 GEMM (fallback only) ----------------
__global__ __launch_bounds__(256) void gemm_bt_k(const float* __restrict__ A, int lda,
                                                 const float* __restrict__ W, int ldw,
                                                 const float* __restrict__ addsrc,
                                                 float* __restrict__ C, int ldc,
                                                 int N, int K) {
  const int tid  = threadIdx.x;
  const int srow = tid >> 1;
  const int skg  = (tid & 1) << 1;
  const int bm = blockIdx.x << 7;
  const int bn = blockIdx.y << 7;
  const int wid = tid >> 6;
  const int lane = tid & 63;
  const int wm = (wid >> 1) << 6;
  const int wn = (wid & 1) << 6;
  const int fr = lane & 15;
  const int kg = lane >> 4;

  __shared__ bf16x8 lA[4][128];
  __shared__ bf16x8 lB[4][128];

  f32x4 zero4 = {0.f, 0.f, 0.f, 0.f};
  f32x4 acc[4][4];
#pragma unroll
  for (int i = 0; i < 4; ++i)
#pragma unroll
    for (int j = 0; j < 4; ++j) acc[i][j] = zero4;

  const bool wvalid = (bn + srow) < N;
  const float* gA = A + (size_t)(bm + srow) * lda + (skg << 3);
  const float* gW = W + (size_t)(wvalid ? (bn + srow) : 0) * ldw + (skg << 3);

  for (int k0 = 0; k0 < K; k0 += 32) {
    float4 a0 = *(const float4*)(gA + k0);
    float4 a1 = *(const float4*)(gA + k0 + 4);
    float4 a2 = *(const float4*)(gA + k0 + 8);
    float4 a3 = *(const float4*)(gA + k0 + 12);
    float4 w0 = make_float4(0.f, 0.f, 0.f, 0.f), w1 = w0, w2 = w0, w3 = w0;
    if (wvalid) {
      w0 = *(const float4*)(gW + k0);
      w1 = *(const float4*)(gW + k0 + 4);
      w2 = *(const float4*)(gW + k0 + 8);
      w3 = *(const float4*)(gW + k0 + 12);
    }
    __syncthreads();
    lA[skg][srow]     = pack8(a0, a1);
    lA[skg + 1][srow] = pack8(a2, a3);
    lB[skg][srow]     = pack8(w0, w1);
    lB[skg + 1][srow] = pack8(w2, w3);
    __syncthreads();

    bf16x8 af[4], bf_[4];
#pragma unroll
    for (int mi = 0; mi < 4; ++mi) af[mi] = lA[kg][wm + (mi << 4) + fr];
#pragma unroll
    for (int ni = 0; ni < 4; ++ni) bf_[ni] = lB[kg][wn + (ni << 4) + fr];
#pragma unroll
    for (int mi = 0; mi < 4; ++mi)
#pragma unroll
      for (int ni = 0; ni < 4; ++ni)
        acc[mi][ni] = __builtin_amdgcn_mfma_f32_16x16x32_bf16(af[mi], bf_[ni], acc[mi][ni], 0, 0, 0);
  }

#pragma unroll
  for (int mi = 0; mi < 4; ++mi)
#pragma unroll
    for (int ni = 0; ni < 4; ++ni) {
      int n = bn + wn + (ni << 4) + fr;
      if (n < N) {
#pragma unroll
        for (int i = 0; i < 4; ++i) {
          int m = bm + wm + (mi << 4) + (kg << 2) + i;
          size_t off = (size_t)m * ldc + n;
          float v = acc[mi][ni][i];
          if (addsrc) v += addsrc[off];
          C[off] = v;
        }
      }
    }
}

// ---------------- chunk-parallel scan ----------------
#define NCH 32
#define CHL 32

__global__ __launch_bounds__(256) void scan_p1f_k(const float* __restrict__ dtv,
                                                  const float* __restrict__ u,
                                                  const float* __restrict__ dbc,
                                                  const float* __restrict__ A_log,
                                                  float* __restrict__ Pg,
                                                  float* __restrict__ qg) {
  int tid = threadIdx.x;
  int s = tid & 15, dg = tid >> 4;
  int d = (blockIdx.x << 4) + dg;
  int c = blockIdx.y;
  int l0 = c << 5;
  float A = -__expf(A_log[d * 16 + s]);
  float P = 1.f, q = 0.f;
#pragma unroll 4
  for (int i = 0; i < CHL; ++i) {
    int l = l0 + i;
    size_t rd = (size_t)l * 2048 + d;
    float dt = dtv[rd];
    float dA = __expf(dt * A);
    P *= dA;
    q = fmaf(dA, q, dt * u[rd] * dbc[l * 96 + 64 + s]);
  }
  size_t o = (size_t)c * 32768 + d * 16 + s;
  Pg[o] = P;
  qg[o] = q;
}

__global__ __launch_bounds__(256) void scan_p3f_k(const float* __restrict__ dtv,
                                                  const float* __restrict__ u,
                                                  const float* __restrict__ dbc,
                                                  const float* __restrict__ xz,
                                                  const float* __restrict__ A_log,
                                                  const float* __restrict__ Dp,
                                                  const float* __restrict__ Pg,
                                                  const float* __restrict__ qg,
                                                  unsigned short* __restrict__ y16) {
  int tid = threadIdx.x;
  int s = tid & 15, dg = tid >> 4;
  int d = (blockIdx.x << 4) + dg;
  int c = blockIdx.y;
  int l0 = c << 5;
  float A = -__expf(A_log[d * 16 + s]);
  float dpar = Dp[d];
  float h = 0.f;
  for (int cc = 0; cc < c; ++cc) {
    size_t o = (size_t)cc * 32768 + d * 16 + s;
    h = fmaf(Pg[o], h, qg[o]);
  }
#pragma unroll 4
  for (int i = 0; i < CHL; ++i) {
    int l = l0 + i;
    size_t rd = (size_t)l * 2048 + d;
    float dt = dtv[rd];
    float uv = u[rd];
    float dA = __expf(dt * A);
    h = fmaf(dA, h, dt * uv * dbc[l * 96 + 64 + s]);
    float p = h * dbc[l * 96 + 80 + s];
    p += __shfl_xor(p, 1); p += __shfl_xor(p, 2);
    p += __shfl_xor(p, 4); p += __shfl_xor(p, 8);
    if (s == 0) {
      float zv = xz[(size_t)l * 4096 + 2048 + d];
      float sig = 1.0f / (1.0f + __expf(-zv));
      y16[rd] = (unsigned short)f2bf((p + uv * dpar) * (zv * sig));
    }
  }
}

// fallback scan
__global__ __launch_bounds__(256) void scan_p1_k(const float* __restrict__ dtr,
                                                 const float* __restrict__ u,
                                                 const float* __restrict__ dbc,
                                                 const float* __restrict__ A_log,
                                                 const float* __restrict__ dtb,
                                                 float* __restrict__ Pg,
                                                 float* __restrict__ qg) {
  int tid = threadIdx.x;
  int s = tid & 15, dg = tid >> 4;
  int d = (blockIdx.x << 4) + dg;
  int c = blockIdx.y;
  int l0 = c << 5;
  float A = -__expf(A_log[d * 16 + s]);
  float bias = dtb[d];
  float P = 1.f, q = 0.f;
#pragma unroll 4
  for (int i = 0; i < CHL; ++i) {
    int l = l0 + i;
    float dt = softplus_f(dtr[(size_t)l * 2048 + d] + bias);
    float dA = __expf(dt * A);
    P *= dA;
    q = fmaf(dA, q, dt * u[(size_t)l * 2048 + d] * dbc[l * 96 + 64 + s]);
  }
  size_t o = (size_t)c * 32768 + d * 16 + s;
  Pg[o] = P;
  qg[o] = q;
}

__global__ __launch_bounds__(256) void scan_p2_k(const float* __restrict__ Pg,
                                                 const float* __restrict__ qg,
                                                 float* __restrict__ hst) {
  int idx = blockIdx.x * 256 + threadIdx.x;
  float h = 0.f;
#pragma unroll
  for (int c = 0; c < NCH; ++c) {
    size_t o = (size_t)c * 32768 + idx;
    hst[o] = h;
    h = fmaf(Pg[o], h, qg[o]);
  }
}

__global__ __launch_bounds__(256) void scan_p3_k(const float* __restrict__ dtr,
                                                 const float* __restrict__ u,
                                                 const float* __restrict__ dbc,
                                                 const float* __restrict__ xz,
                                                 const float* __restrict__ A_log,
                                                 const float* __restrict__ Dp,
                                                 const float* __restrict__ dtb,
                                                 const float* __restrict__ hst,
                                                 float* __restrict__ y) {
  int tid = threadIdx.x;
  int s = tid & 15, dg = tid >> 4;
  int d = (blockIdx.x << 4) + dg;
  int c = blockIdx.y;
  int l0 = c << 5;
  float A = -__expf(A_log[d * 16 + s]);
  float dpar = Dp[d];
  float bias = dtb[d];
  float h = hst[(size_t)c * 32768 + d * 16 + s];
#pragma unroll 4
  for (int i = 0; i < CHL; ++i) {
    int l = l0 + i;
    size_t rd = (size_t)l * 2048 + d;
    float dt = softplus_f(dtr[rd] + bias);
    float uv = u[rd];
    float dA = __expf(dt * A);
    h = fmaf(dA, h, dt * uv * dbc[l * 96 + 64 + s]);
    float p = h * dbc[l * 96 + 80 + s];
    p += __shfl_xor(p, 1); p += __shfl_xor(p, 2);
    p += __shfl_xor(p, 4); p += __shfl_xor(p, 8);
    if (s == 0) {
      float zv = xz[(size_t)l * 4096 + 2048 + d];
      float sig = 1.0f / (1.0f + __expf(-zv));
      y[rd] = (p + uv * dpar) * (zv * sig);
    }
  }
}

// ---------------- host launch ----------------
extern "C" void kernel_launch(void* const* d_in, const int* in_sizes, int n_in,
                              void* d_out, int out_size, void* d_ws, size_t ws_size,
                              hipStream_t stream) {
  const int*   tokens = (const int*)d_in[0];
  const float* embed  = (const float*)d_in[1];
  const float* norm_w = (const float*)d_in[2];
  const float* in_w   = (const float*)d_in[3];
  const float* conv_w = (const float*)d_in[4];
  const float* conv_b = (const float*)d_in[5];
  const float* x_w    = (const float*)d_in[6];
  const float* dt_w   = (const float*)d_in[7];
  const float* dt_b   = (const float*)d_in[8];
  const float* A_log  = (const float*)d_in[9];
  const float* D_par  = (const float*)d_in[10];
  const float* out_w  = (const float*)d_in[11];
  const float* normf  = (const float*)d_in[12];
  const float* lm_w   = (const float*)d_in[13];

  float* out = (float*)d_out;
  // f32 scratch in d_out (dead before lm_head writes it)
  float* x    = out;                    // 1M
  float* xz   = x    + 1024 * 1024;    // 4M
  float* u    = xz   + 1024 * 4096;    // 2M
  float* dtv  = u    + 1024 * 2048;    // 2M
  float* dbc  = dtv  + 1024 * 2048;    // 96K
  float* Pg   = dbc  + 1024 * 96;      // 1M
  float* qg   = Pg   + 32 * 32768;     // 1M
  float* hst  = qg   + 32 * 32768;     // 1M (fallback)
  float* xn_f = hst  + 32 * 32768;     // 1M (fallback)
  float* y_f  = xn_f + 1024 * 1024;    // 2M (fallback)
  unsigned short* xn16  = (unsigned short*)(y_f + 1024 * 2048);
  unsigned short* u16   = xn16 + 1024 * 1024;
  unsigned short* y16   = u16  + 1024 * 2048;
  unsigned short* dbc16 = y16  + 1024 * 2048;
  float* part_op = (float*)(dbc16 + 1024 * 96);   // 4x 1M f32 = 16MB
  float* part_xp = part_op + 4 * 1048576;         // 4x 98304 f32
  // ends ~88.4 MB < 131 MB

  // d_ws: bf16 weights + xnf
  unsigned short* inw16 = (unsigned short*)d_ws;      // 16,777,216
  unsigned short* oww16 = inw16 + 16777216;           //  8,388,608
  unsigned short* xw16  = oww16 + 8388608;            //    786,432
  unsigned short* dtw16 = xw16  + 786432;             //    524,288
  unsigned short* lmw16 = dtw16 + 524288;             // 32,768,000
  unsigned short* xnf16 = lmw16 + 32768000;           //  1,048,576
  const size_t need = (size_t)(16777216 + 8388608 + 786432 + 524288 + 32768000 + 1048576) * 2;
  const bool fast = ws_size >= need;

  if (fast) {
    cvt_all_k<<<4096, 256, 0, stream>>>(in_w, inw16, 2097152,
                                        out_w, oww16, 1048576,
                                        x_w, xw16, 98304,
                                        dt_w, dtw16, 65536,
                                        lm_w, lmw16, 4096000);
    embed_rms_k<<<1024, 256, 0, stream>>>(tokens, embed, norm_w, x, xn16);

    for (int i = 0; i < 4; ++i) {
      if (i > 0) rmsnorm16_k<<<1024, 256, 0, stream>>>(x, norm_w + i * 1024, xn16);
      gemm16_k<<<256, 256, 0, stream>>>(xn16, 1024, inw16 + (size_t)i * 4194304, 1024,
                                        nullptr, nullptr, xz, 4096, nullptr, 8, 4096, 1024);
      conv_silu_k<<<8192, 256, 0, stream>>>(xz, conv_w + i * 8192, conv_b + i * 2048, u, u16);
      gemm16sk_k<<<dim3(8, 4), 256, 0, stream>>>(u16, 2048, xw16 + (size_t)i * 196608, 2048,
                                                 part_xp, 96, 8, 96, 512, 1024);
      reduce_xp_k<<<384, 256, 0, stream>>>(part_xp, dbc, dbc16);
      gemm16_k<<<128, 256, 0, stream>>>(dbc16, 96, dtw16 + (size_t)i * 131072, 64,
                                        nullptr, dt_b + i * 2048, dtv, 2048, nullptr, 8, 2048, 64);
      scan_p1f_k<<<dim3(128, NCH), 256, 0, stream>>>(dtv, u, dbc, A_log + i * 32768, Pg, qg);
      scan_p3f_k<<<dim3(128, NCH), 256, 0, stream>>>(dtv, u, dbc, xz, A_log + i * 32768,
                                                     D_par + i * 2048, Pg, qg, y16);
      gemm16sk_k<<<dim3(64, 4), 256, 0, stream>>>(y16, 2048, oww16 + (size_t)i * 2097152, 2048,
                                                  part_op, 1024, 8, 1024, 512, 1024);
      reduce_op_k<<<1024, 256, 0, stream>>>(part_op, x);
    }

    rmsnorm16_k<<<1024, 256, 0, stream>>>(x, normf, xnf16);
    gemm256_k<<<500, 512, 0, stream>>>(xnf16, 1024, lmw16, 1024, out, 32000, 4, 32000, 1024);
  } else {
    // fallback: round-1 proven path (f32 staging GEMM)
    float* xnf_f = (float*)d_ws;
    embed_rms_k<<<1024, 256, 0, stream>>>(tokens, embed, norm_w, x, xn16);
    for (int i = 0; i < 4; ++i) {
      rmsnorm_k<<<1024, 256, 0, stream>>>(x, norm_w + i * 1024, xn_f);
      gemm_bt_k<<<dim3(8, 32), 256, 0, stream>>>(xn_f, 1024, in_w + (size_t)i * 4194304, 1024,
                                                 nullptr, xz, 4096, 4096, 1024);
      conv_silu_k<<<8192, 256, 0, stream>>>(xz, conv_w + i * 8192, conv_b + i * 2048, u, nullptr);
      gemm_bt_k<<<dim3(8, 1), 256, 0, stream>>>(u, 2048, x_w + (size_t)i * 196608, 2048,
                                                nullptr, dbc, 96, 96, 2048);
      gemm_bt_k<<<dim3(8, 16), 256, 0, stream>>>(dbc, 96, dt_w + (size_t)i * 131072, 64,
                                                 nullptr, dtv, 2048, 2048, 64);
      scan_p1_k<<<dim3(128, NCH), 256, 0, stream>>>(dtv, u, dbc, A_log + i * 32768,
                                                    dt_b + i * 2048, Pg, qg);
      scan_p2_k<<<128, 256, 0, stream>>>(Pg, qg, hst);
      scan_p3_k<<<dim3(128, NCH), 256, 0, stream>>>(dtv, u, dbc, xz, A_log + i * 32768,
                                                    D_par + i * 2048, dt_b + i * 2048, hst, y_f);
      gemm_bt_k<<<dim3(8, 8), 256, 0, stream>>>(y_f, 2048, out_w + (size_t)i * 2097152, 2048,
                                                x, x, 1024, 1024, 2048);
    }
    rmsnorm_k<<<1024, 256, 0, stream>>>(x, normf, xnf_f);
    gemm_bt_k<<<dim3(8, 250), 256, 0, stream>>>(xnf_f, 1024, lm_w, 1024,
                                                nullptr, out, 32000, 32000, 1024);
  }
}